// Round 12
// baseline (1174.999 us; speedup 1.0000x reference)
//
#include <hip/hip_runtime.h>

#define T_LEN   131072
#define IN_DIM  256
#define HD      64
#define PD      32
#define NLAY    4
#define CHUNK   128
#define NBLK    (T_LEN / CHUNK)   // 1024
#define ASTR    68                // LDS row stride: 68 % 32 == 4 -> conflict-free column b128

typedef __attribute__((ext_vector_type(8))) short bf16x8;
typedef __attribute__((ext_vector_type(4))) float f32x4;

union FragU { uint4 q; bf16x8 v; };

__device__ __forceinline__ unsigned splitpack(float x) {
    unsigned xb = __float_as_uint(x);
    unsigned hb = (xb + 0x8000u) & 0xffff0000u;
    float lf = x - __uint_as_float(hb);
    unsigned lb = (__float_as_uint(lf) + 0x8000u) >> 16;
    return (hb >> 16) | (lb << 16);
}

__device__ __forceinline__ void packAB(float4 a0, float4 a1, bf16x8& hi, bf16x8& lo) {
    unsigned p0 = splitpack(a0.x), p1 = splitpack(a0.y);
    unsigned p2 = splitpack(a0.z), p3 = splitpack(a0.w);
    unsigned p4 = splitpack(a1.x), p5 = splitpack(a1.y);
    unsigned p6 = splitpack(a1.z), p7 = splitpack(a1.w);
    union { bf16x8 v; unsigned u[4]; } H, L;
    H.u[0] = (p0 & 0xffffu) | (p1 << 16);
    H.u[1] = (p2 & 0xffffu) | (p3 << 16);
    H.u[2] = (p4 & 0xffffu) | (p5 << 16);
    H.u[3] = (p6 & 0xffffu) | (p7 << 16);
    L.u[0] = (p0 >> 16) | (p1 & 0xffff0000u);
    L.u[1] = (p2 >> 16) | (p3 & 0xffff0000u);
    L.u[2] = (p4 >> 16) | (p5 & 0xffff0000u);
    L.u[3] = (p6 >> 16) | (p7 & 0xffff0000u);
    hi = H.v; lo = L.v;
}

#define MFMA3(ACC, AH, AL, BH, BL)                                              \
    ACC = __builtin_amdgcn_mfma_f32_16x16x32_bf16(AH, BH, ACC, 0, 0, 0);        \
    ACC = __builtin_amdgcn_mfma_f32_16x16x32_bf16(AH, BL, ACC, 0, 0, 0);        \
    ACC = __builtin_amdgcn_mfma_f32_16x16x32_bf16(AL, BH, ACC, 0, 0, 0);

__device__ __forceinline__ int kmap(int q, int j) {
    return (j < 4) ? (q * 4 + j) : (16 + q * 4 + (j - 4));
}

// ---------------------------------------------------------------- K0a: setup + zero stats/flags
__global__ __launch_bounds__(512) void ssm_k0a(
    const float* __restrict__ Lre, const float* __restrict__ Lim,
    const float* __restrict__ logstep,
    float* __restrict__ Lbar, float* __restrict__ Ldt, float* __restrict__ stats,
    int* __restrict__ flags)
{
    int tid = threadIdx.x;
    if (tid < NLAY * PD) {
        int l = tid >> 5, p = tid & 31;
        float dt = expf(logstep[l * PD + p]);
        float lr = Lre[l * PD + p], li = Lim[l * PD + p];
        float ldr = lr * dt, ldi = li * dt;
        Ldt[tid * 2] = ldr; Ldt[tid * 2 + 1] = ldi;
        float e = expf(ldr);
        float sn, cs; sincosf(ldi, &sn, &cs);
        Lbar[tid * 2] = e * cs; Lbar[tid * 2 + 1] = e * sn;
    }
    if (tid < NLAY * 128) stats[tid] = 0.0f;
    for (int i = tid; i < NLAY * NBLK; i += 512) flags[i] = 0;
}

// ---------------------------------------------------------------- K0b: weight fragment builder (unchanged)
__global__ __launch_bounds__(256) void ssm_k0b(
    const float* __restrict__ Lre, const float* __restrict__ Lim,
    const float* __restrict__ logstep,
    const float* __restrict__ Bre, const float* __restrict__ Bim,
    const float* __restrict__ Cre, const float* __restrict__ Cim,
    const float* __restrict__ w1, const float* __restrict__ w2,
    const float* __restrict__ enc_w, const int* __restrict__ gptr,
    unsigned* __restrict__ fragE, unsigned* __restrict__ fragL)
{
    int fi = blockIdx.x * 256 + threadIdx.x;
    if (fi >= 10240) return;
    int g = gptr[0];
    int mat, lay = 0, rem;
    unsigned* outp;
    if (fi < 2048) { mat = 0; rem = fi; outp = fragE + rem * 8; }
    else {
        int t = fi - 2048;
        lay = t / 2048;
        int r2 = t % 2048;
        mat = 1 + r2 / 512;
        rem = r2 % 512;
        outp = fragL + ((size_t)(lay * 4 + (mat - 1)) * 512 + rem) * 8;
    }
    int ks = rem / 256;
    int nt = (rem / 64) & 3;
    int lane = rem & 63;
    int q = lane >> 4;
    int n = nt * 16 + (lane & 15);

    float vals[8];
#pragma unroll
    for (int j = 0; j < 8; ++j) {
        int k = ks * 32 + kmap(q, j);
        float v;
        if (mat == 0) {
            v = (n < 56) ? enc_w[(size_t)(g * 56 + n) * IN_DIM + k] : 0.0f;
        } else if (mat == 1) {
            int p = n >> 1;
            float dt = expf(logstep[lay * PD + p]);
            float lr = Lre[lay * PD + p], li = Lim[lay * PD + p];
            float e = expf(lr * dt);
            float sn, cs; sincosf(li * dt, &sn, &cs);
            float den = lr * lr + li * li;
            float nr = e * cs - 1.0f, ni = e * sn;
            float fr = (nr * lr + ni * li) / den, fimag = (ni * lr - nr * li) / den;
            float br = Bre[(lay * PD + p) * HD + k], bi = Bim[(lay * PD + p) * HD + k];
            v = (n & 1) ? (fr * bi + fimag * br) : (fr * br - fimag * bi);
        } else if (mat == 2) {
            int p = k >> 1;
            v = (k & 1) ? -Cim[((size_t)lay * HD + n) * PD + p]
                        :  Cre[((size_t)lay * HD + n) * PD + p];
        } else if (mat == 3) {
            v = w1[((size_t)lay * HD + n) * HD + k];
        } else {
            v = w2[((size_t)lay * HD + n) * HD + k];
        }
        vals[j] = v;
    }
    unsigned p8[8];
#pragma unroll
    for (int j = 0; j < 8; ++j) p8[j] = splitpack(vals[j]);
#pragma unroll
    for (int w = 0; w < 4; ++w) {
        unsigned p0 = p8[2 * w], p1 = p8[2 * w + 1];
        outp[w]     = (p0 & 0xffffu) | (p1 << 16);
        outp[4 + w] = (p0 >> 16) | (p1 & 0xffff0000u);
    }
}

// ---------------------------------------------------------------- K5: stats reduce
__global__ __launch_bounds__(64) void ssm_k5_reduce(
    const float* __restrict__ part, float* __restrict__ statsL)
{
    int c = blockIdx.x;
    int lane = threadIdx.x;
    float s = 0.0f;
#pragma unroll
    for (int j = 0; j < 4; ++j) {
        float4 v = *(const float4*)&part[c * 1024 + j * 256 + lane * 4];
        s += v.x + v.y + v.z + v.w;
    }
#pragma unroll
    for (int m = 1; m < 64; m <<= 1) s += __shfl_xor(s, m, 64);
    if (lane == 0) statsL[c] = s;
}

// ---------------------------------------------------------------- K1: encoder (unchanged from R10)
__global__ __launch_bounds__(512, 4) void ssm_k1_encoder(
    const float* __restrict__ x, const int* __restrict__ gptr,
    const unsigned* __restrict__ fragE, const float* __restrict__ enc_b,
    const float* __restrict__ ctx_emb,
    float* __restrict__ h, float* __restrict__ part)
{
    __shared__ float sp1[512], sp2[512];
    int tid = threadIdx.x;
    int l = tid & 63, w = tid >> 6;
    int cq = l >> 4, cr = l & 15;
    int g = gptr[0];
    size_t r0 = (size_t)blockIdx.x * 128;
    int arow = 16 * w + cr;
    const float* xrow = &x[(r0 + arow) * IN_DIM];
    const f32x4 fzero = {0.f, 0.f, 0.f, 0.f};

    float4 cur[16];
#pragma unroll
    for (int kt = 0; kt < 4; ++kt)
#pragma unroll
        for (int ks = 0; ks < 2; ++ks) {
            cur[kt * 4 + 2 * ks]     = *(const float4*)&xrow[kt * 64 + ks * 32 + cq * 4];
            cur[kt * 4 + 2 * ks + 1] = *(const float4*)&xrow[kt * 64 + ks * 32 + cq * 4 + 16];
        }

    f32x4 acc[4];
#pragma unroll
    for (int nt = 0; nt < 4; ++nt) acc[nt] = fzero;

#pragma unroll
    for (int kt = 0; kt < 4; ++kt)
#pragma unroll
        for (int ks = 0; ks < 2; ++ks) {
            bf16x8 ah, al;
            packAB(cur[kt * 4 + 2 * ks], cur[kt * 4 + 2 * ks + 1], ah, al);
            int ksg = kt * 2 + ks;
#pragma unroll
            for (int nt = 0; nt < 4; ++nt) {
                const uint4* wf = (const uint4*)&fragE[((size_t)(ksg * 4 + nt) * 64 + l) * 8];
                FragU BH, BL; BH.q = wf[0]; BL.q = wf[1];
                MFMA3(acc[nt], ah, al, BH.v, BL.v);
            }
        }
#pragma unroll
    for (int nt = 0; nt < 4; ++nt) {
        int ch = nt * 16 + cr;
        float eb = (ch < 56) ? enc_b[g * 56 + ch] : 0.0f;
        bool isctx = (ch >= 56);
        float cv = isctx ? ctx_emb[g * 8 + (ch - 56)] : 0.0f;
        float v1 = 0.0f, v2 = 0.0f;
#pragma unroll
        for (int r = 0; r < 4; ++r) {
            float val = isctx ? cv : (acc[nt][r] + eb);
            h[(r0 + 16 * w + 4 * cq + r) * HD + ch] = val;
            v1 += val; v2 += val * val;
        }
        v1 += __shfl_xor(v1, 16, 64); v2 += __shfl_xor(v2, 16, 64);
        v1 += __shfl_xor(v1, 32, 64); v2 += __shfl_xor(v2, 32, 64);
        if (l < 16) { sp1[w * 64 + ch] = v1; sp2[w * 64 + ch] = v2; }
    }
    __syncthreads();
    if (tid < 64) {
        float s1 = 0.0f, s2 = 0.0f;
#pragma unroll
        for (int ww = 0; ww < 8; ++ww) { s1 += sp1[ww * 64 + tid]; s2 += sp2[ww * 64 + tid]; }
        part[tid * 1024 + blockIdx.x]        = s1;
        part[(64 + tid) * 1024 + blockIdx.x] = s2;
    }
}

// ---------------------------------------------------------------- KL: fused layer (decoupled lookback, regular launch)
// 1024 blocks x 512 threads; block owns one 128-row chunk.
// Phase A: hn -> Bu GEMM -> local scan in LDS; publish carry (flag 1).
// Lookback: wave 0 accumulates exclusive prefix from predecessors; publish inclusive (flag 2).
// Phase C: fixup + C-proj + gelu + GLU + residual/decoder, all from LDS.
template <bool LAST>
__global__ __launch_bounds__(512, 4) void ssm_kl(
    float* __restrict__ h, const float* __restrict__ stats,
    const float* __restrict__ nscale, const float* __restrict__ nbias,
    const unsigned* __restrict__ fragL,
    const float* __restrict__ Lbar, const float* __restrict__ Ldt,
    float* __restrict__ carryV, float* __restrict__ inclV, int* __restrict__ flags,
    const float* __restrict__ Dv, const float* __restrict__ b1,
    const float* __restrict__ b2, float* __restrict__ part,
    const float* __restrict__ dec_w, const float* __restrict__ dec_b,
    float* __restrict__ outp, int lay)
{
    __shared__ __attribute__((aligned(16))) float bf[128 * ASTR];   // 34816 B, reused as g (uint)
    __shared__ float lsa[HD], lsb[HD], lsd[HD], lld[HD], lpc[HD];
    __shared__ float sp1[512], sp2[512];
    int tid = threadIdx.x;
    int bid = blockIdx.x;
    int l = tid & 63, w = tid >> 6;
    int cq = l >> 4, cr = l & 15;
    size_t r0 = (size_t)bid * CHUNK;
    int arow = 16 * w + cr;
    const f32x4 fzero = {0.f, 0.f, 0.f, 0.f};

    if (tid < HD) {
        float s1 = stats[lay * 128 + tid], s2 = stats[lay * 128 + 64 + tid];
        float mu = s1 * (1.0f / T_LEN);
        float var = fmaxf(s2 * (1.0f / T_LEN) - mu * mu, 0.0f);
        float sc = nscale[lay * HD + tid] * rsqrtf(var + 1e-5f);
        lsa[tid] = sc;
        lsb[tid] = nbias[lay * HD + tid] - mu * sc;
        lsd[tid] = Dv[lay * HD + tid];
        lld[tid] = Ldt[lay * 64 + tid];
    }
    __syncthreads();

    // ---- phase A: hn (direct A-frag) -> Bu GEMM -> bf
    const unsigned* fB = fragL + (size_t)(lay * 4 + 0) * 4096;
    {
        const float* hrowp = &h[(r0 + arow) * HD];
        f32x4 acc[4];
#pragma unroll
        for (int nt = 0; nt < 4; ++nt) acc[nt] = fzero;
#pragma unroll
        for (int ks = 0; ks < 2; ++ks) {
            int k0 = ks * 32 + cq * 4;
            float4 c0 = *(const float4*)&hrowp[k0];
            float4 c1 = *(const float4*)&hrowp[k0 + 16];
            c0.x = c0.x * lsa[k0]      + lsb[k0];
            c0.y = c0.y * lsa[k0 + 1]  + lsb[k0 + 1];
            c0.z = c0.z * lsa[k0 + 2]  + lsb[k0 + 2];
            c0.w = c0.w * lsa[k0 + 3]  + lsb[k0 + 3];
            c1.x = c1.x * lsa[k0 + 16] + lsb[k0 + 16];
            c1.y = c1.y * lsa[k0 + 17] + lsb[k0 + 17];
            c1.z = c1.z * lsa[k0 + 18] + lsb[k0 + 18];
            c1.w = c1.w * lsa[k0 + 19] + lsb[k0 + 19];
            bf16x8 ah, al;
            packAB(c0, c1, ah, al);
#pragma unroll
            for (int nt = 0; nt < 4; ++nt) {
                const uint4* wf = (const uint4*)&fB[((size_t)(ks * 4 + nt) * 64 + l) * 8];
                FragU BH, BL; BH.q = wf[0]; BL.q = wf[1];
                MFMA3(acc[nt], ah, al, BH.v, BL.v);
            }
        }
#pragma unroll
        for (int nt = 0; nt < 4; ++nt)
#pragma unroll
            for (int r = 0; r < 4; ++r)
                bf[(16 * w + 4 * cq + r) * ASTR + nt * 16 + cr] = acc[nt][r];
    }
    __syncthreads();

    // ---- local scan + decoupled lookback (wave 0)
    if (tid < 64) {
        int p = l >> 1;
        float Lr = Lbar[(lay * PD + p) * 2];
        float Lj = Lbar[(lay * PD + p) * 2 + 1];
        float csn = (l & 1) ? Lj : -Lj;
        float xv = 0.0f;
        for (int t = 0; t < CHUNK; ++t) {
            float b = bf[t * ASTR + l];
            float xo = __shfl_xor(xv, 1, 64);
            xv = Lr * xv + csn * xo + b;
            bf[t * ASTR + l] = xv;
        }
        // publish aggregate
        carryV[(size_t)bid * 64 + l] = xv;
        float pc_ = 0.0f;
        if (bid == 0) {
            inclV[l] = xv;
            if (l == 0)
                __hip_atomic_store(&flags[bid], 2, __ATOMIC_RELEASE, __HIP_MEMORY_SCOPE_AGENT);
        } else {
            if (l == 0)
                __hip_atomic_store(&flags[bid], 1, __ATOMIC_RELEASE, __HIP_MEMORY_SCOPE_AGENT);
            float ldr = lld[2 * p], ldi = lld[2 * p + 1];
            float er = __expf(ldr * (float)CHUNK);
            float an = ldi * (float)CHUNK;
            float lcr = er * __cosf(an), lci = er * __sinf(an);   // Lc = L^CHUNK
            float mr = 1.0f, mi = 0.0f;                            // Lc^0
            int j = bid - 1;
            while (true) {
                int f = 0;
                if (l == 0) {
                    do {
                        f = __hip_atomic_load(&flags[j], __ATOMIC_ACQUIRE, __HIP_MEMORY_SCOPE_AGENT);
                    } while (f == 0);
                }
                f = __shfl(f, 0, 64);
                const float* src = (f == 2) ? &inclV[(size_t)j * 64] : &carryV[(size_t)j * 64];
                float v = __hip_atomic_load(&src[l], __ATOMIC_RELAXED, __HIP_MEMORY_SCOPE_AGENT);
                float vo = __shfl_xor(v, 1, 64);
                float cs2 = (l & 1) ? mi : -mi;
                pc_ += mr * v + cs2 * vo;
                if (f == 2) break;
                float nmr = mr * lcr - mi * lci;
                float nmi = mr * lci + mi * lcr;
                mr = nmr; mi = nmi;
                --j;
            }
            // inclusive = Lc * pc_ + agg
            float pco = __shfl_xor(pc_, 1, 64);
            float csl = (l & 1) ? lci : -lci;
            float inc = lcr * pc_ + csl * pco + xv;
            inclV[(size_t)bid * 64 + l] = inc;
            if (l == 0)
                __hip_atomic_store(&flags[bid], 2, __ATOMIC_RELEASE, __HIP_MEMORY_SCOPE_AGENT);
        }
        lpc[l] = pc_;
    }
    __syncthreads();

    // ---- phase C: fixup + C-proj GEMM
    const unsigned* fC = fragL + (size_t)(lay * 4 + 1) * 4096;
    const unsigned* f1 = fragL + (size_t)(lay * 4 + 2) * 4096;
    const unsigned* f2 = fragL + (size_t)(lay * 4 + 3) * 4096;
    unsigned* act = (unsigned*)bf;

    f32x4 yacc[4];
#pragma unroll
    for (int nt = 0; nt < 4; ++nt) yacc[nt] = fzero;
    {
        const float* brow = &bf[arow * ASTR];
        float tt = (float)(arow + 1);
#pragma unroll
        for (int ks = 0; ks < 2; ++ks) {
            int k0 = ks * 32 + cq * 4;
            float4 v0 = *(const float4*)&brow[k0];
            float4 v1 = *(const float4*)&brow[k0 + 16];
            {
                float e1 = __expf(lld[k0] * tt), an = lld[k0 + 1] * tt;
                float prr = e1 * __cosf(an), pri = e1 * __sinf(an);
                v0.x += prr * lpc[k0] - pri * lpc[k0 + 1];
                v0.y += prr * lpc[k0 + 1] + pri * lpc[k0];
            }
            {
                float e1 = __expf(lld[k0 + 2] * tt), an = lld[k0 + 3] * tt;
                float prr = e1 * __cosf(an), pri = e1 * __sinf(an);
                v0.z += prr * lpc[k0 + 2] - pri * lpc[k0 + 3];
                v0.w += prr * lpc[k0 + 3] + pri * lpc[k0 + 2];
            }
            {
                float e1 = __expf(lld[k0 + 16] * tt), an = lld[k0 + 17] * tt;
                float prr = e1 * __cosf(an), pri = e1 * __sinf(an);
                v1.x += prr * lpc[k0 + 16] - pri * lpc[k0 + 17];
                v1.y += prr * lpc[k0 + 17] + pri * lpc[k0 + 16];
            }
            {
                float e1 = __expf(lld[k0 + 18] * tt), an = lld[k0 + 19] * tt;
                float prr = e1 * __cosf(an), pri = e1 * __sinf(an);
                v1.z += prr * lpc[k0 + 18] - pri * lpc[k0 + 19];
                v1.w += prr * lpc[k0 + 19] + pri * lpc[k0 + 18];
            }
            bf16x8 ah, al;
            packAB(v0, v1, ah, al);
#pragma unroll
            for (int nt = 0; nt < 4; ++nt) {
                const uint4* wf = (const uint4*)&fC[((size_t)(ks * 4 + nt) * 64 + l) * 8];
                FragU BH, BL; BH.q = wf[0]; BL.q = wf[1];
                MFMA3(yacc[nt], ah, al, BH.v, BL.v);
            }
        }
    }

    // gelu(2y + hn*D) -> g split-packed into act (wave-band rows: safe reuse of bf)
    float hrow[16];
#pragma unroll
    for (int nt = 0; nt < 4; ++nt) {
        int ch = nt * 16 + cr;
        float sav = lsa[ch], sbv = lsb[ch], dvv = lsd[ch];
#pragma unroll
        for (int r = 0; r < 4; ++r) {
            int row = 16 * w + 4 * cq + r;
            float hv = h[(r0 + row) * HD + ch];
            hrow[nt * 4 + r] = hv;
            float t = 2.0f * yacc[nt][r] + (hv * sav + sbv) * dvv;
            float u2 = 1.5957691216057308f * (t + 0.044715f * t * t * t);
            float gv = t / (1.0f + __expf(-u2));
            act[row * ASTR + ch] = splitpack(gv);
        }
    }
    asm volatile("s_waitcnt lgkmcnt(0)" ::: "memory");

    // GLU 2 GEMMs
    f32x4 uacc[4], sacc[4];
#pragma unroll
    for (int nt = 0; nt < 4; ++nt) { uacc[nt] = fzero; sacc[nt] = fzero; }
#pragma unroll
    for (int ks = 0; ks < 2; ++ks) {
        int col = ks * 32 + 4 * cq;
        uint4 a0 = *(const uint4*)&act[arow * ASTR + col];
        uint4 a1 = *(const uint4*)&act[arow * ASTR + col + 16];
        union { bf16x8 v; unsigned u[4]; } H, L;
        H.u[0] = (a0.x & 0xffffu) | (a0.y << 16);
        H.u[1] = (a0.z & 0xffffu) | (a0.w << 16);
        H.u[2] = (a1.x & 0xffffu) | (a1.y << 16);
        H.u[3] = (a1.z & 0xffffu) | (a1.w << 16);
        L.u[0] = (a0.x >> 16) | (a0.y & 0xffff0000u);
        L.u[1] = (a0.z >> 16) | (a0.w & 0xffff0000u);
        L.u[2] = (a1.x >> 16) | (a1.y & 0xffff0000u);
        L.u[3] = (a1.z >> 16) | (a1.w & 0xffff0000u);
#pragma unroll
        for (int nt = 0; nt < 4; ++nt) {
            const uint4* w1f = (const uint4*)&f1[((size_t)(ks * 4 + nt) * 64 + l) * 8];
            FragU BH1, BL1; BH1.q = w1f[0]; BL1.q = w1f[1];
            MFMA3(uacc[nt], H.v, L.v, BH1.v, BL1.v);
            const uint4* w2f = (const uint4*)&f2[((size_t)(ks * 4 + nt) * 64 + l) * 8];
            FragU BH2, BL2; BH2.q = w2f[0]; BL2.q = w2f[1];
            MFMA3(sacc[nt], H.v, L.v, BH2.v, BL2.v);
        }
    }

    // epilogue
    if (LAST) {
        float o0[4] = {0.f, 0.f, 0.f, 0.f}, o1[4] = {0.f, 0.f, 0.f, 0.f};
#pragma unroll
        for (int nt = 0; nt < 4; ++nt) {
            int ch = nt * 16 + cr;
            float bb1 = b1[lay * HD + ch], bb2 = b2[lay * HD + ch];
            float dw0 = dec_w[ch], dw1 = dec_w[64 + ch];
#pragma unroll
            for (int r = 0; r < 4; ++r) {
                float sv = sacc[nt][r] + bb2;
                float sg = 1.0f / (1.0f + __expf(-sv));
                float ho = hrow[nt * 4 + r] + (uacc[nt][r] + bb1) * sg;
                o0[r] += ho * dw0;
                o1[r] += ho * dw1;
            }
        }
#pragma unroll
        for (int r = 0; r < 4; ++r) {
#pragma unroll
            for (int m = 1; m < 16; m <<= 1) {
                o0[r] += __shfl_xor(o0[r], m, 64);
                o1[r] += __shfl_xor(o1[r], m, 64);
            }
        }
        if (cr == 0) {
            float db0 = dec_b[0], db1 = dec_b[1];
#pragma unroll
            for (int r = 0; r < 4; ++r) {
                int row = 16 * w + 4 * cq + r;
                *(float2*)&outp[(r0 + row) * 2] = make_float2(o0[r] + db0, o1[r] + db1);
            }
        }
    } else {
#pragma unroll
        for (int nt = 0; nt < 4; ++nt) {
            int ch = nt * 16 + cr;
            float bb1 = b1[lay * HD + ch], bb2 = b2[lay * HD + ch];
            float v1 = 0.0f, v2 = 0.0f;
#pragma unroll
            for (int r = 0; r < 4; ++r) {
                int row = 16 * w + 4 * cq + r;
                float sv = sacc[nt][r] + bb2;
                float sg = 1.0f / (1.0f + __expf(-sv));
                float ho = hrow[nt * 4 + r] + (uacc[nt][r] + bb1) * sg;
                h[(r0 + row) * HD + ch] = ho;   // in-place: block-own rows
                v1 += ho; v2 += ho * ho;
            }
            v1 += __shfl_xor(v1, 16, 64); v2 += __shfl_xor(v2, 16, 64);
            v1 += __shfl_xor(v1, 32, 64); v2 += __shfl_xor(v2, 32, 64);
            if (l < 16) { sp1[w * 64 + ch] = v1; sp2[w * 64 + ch] = v2; }
        }
        __syncthreads();
        if (tid < 64) {
            float s1 = 0.0f, s2 = 0.0f;
#pragma unroll
            for (int ww = 0; ww < 8; ++ww) { s1 += sp1[ww * 64 + tid]; s2 += sp2[ww * 64 + tid]; }
            part[tid * 1024 + bid]        = s1;
            part[(64 + tid) * 1024 + bid] = s2;
        }
    }
}

// ---------------------------------------------------------------- launch
extern "C" void kernel_launch(void* const* d_in, const int* in_sizes, int n_in,
                              void* d_out, int out_size, void* d_ws, size_t ws_size,
                              hipStream_t stream)
{
    (void)in_sizes; (void)n_in; (void)out_size; (void)ws_size;
    const float* x     = (const float*)d_in[0];
    const int*   gidx  = (const int*)d_in[1];
    const float* enc_w = (const float*)d_in[2];
    const float* enc_b = (const float*)d_in[3];
    const float* ctx   = (const float*)d_in[4];
    const float* Lre   = (const float*)d_in[5];
    const float* Lim   = (const float*)d_in[6];
    const float* Bre   = (const float*)d_in[7];
    const float* Bim   = (const float*)d_in[8];
    const float* Cre   = (const float*)d_in[9];
    const float* Cim   = (const float*)d_in[10];
    const float* Dv    = (const float*)d_in[11];
    const float* lstep = (const float*)d_in[12];
    const float* nsc   = (const float*)d_in[13];
    const float* nbi   = (const float*)d_in[14];
    const float* w1    = (const float*)d_in[15];
    const float* b1    = (const float*)d_in[16];
    const float* w2    = (const float*)d_in[17];
    const float* b2    = (const float*)d_in[18];
    const float* dw    = (const float*)d_in[19];
    const float* db    = (const float*)d_in[20];
    float* out = (float*)d_out;

    float* ws = (float*)d_ws;
    float* h      = ws;  ws += (size_t)T_LEN * HD;
    float* carryV = ws;  ws += (size_t)NBLK * HD;
    float* inclV  = ws;  ws += (size_t)NBLK * HD;
    float* stats  = ws;  ws += NLAY * 128;
    float* Lbar   = ws;  ws += NLAY * PD * 2;
    float* Ldt    = ws;  ws += NLAY * PD * 2;
    int*   flags  = (int*)ws;  ws += NLAY * NBLK;
    unsigned* fragE = (unsigned*)ws;  ws += 16384;
    unsigned* fragL = (unsigned*)ws;  ws += 65536;
    float* part   = ws;  ws += 128 * 1024;

    ssm_k0a<<<1, 512, 0, stream>>>(Lre, Lim, lstep, Lbar, Ldt, stats, flags);
    ssm_k0b<<<40, 256, 0, stream>>>(Lre, Lim, lstep, Bre, Bim, Cre, Cim, w1, w2,
                                    enc_w, gidx, fragE, fragL);
    ssm_k1_encoder<<<1024, 512, 0, stream>>>(x, gidx, fragE, enc_b, ctx, h, part);
    ssm_k5_reduce<<<128, 64, 0, stream>>>(part, stats);
    for (int lay = 0; lay < NLAY; ++lay) {
        int* flagsL = flags + lay * NBLK;
        if (lay < NLAY - 1) {
            ssm_kl<false><<<NBLK, 512, 0, stream>>>(
                h, stats, nsc, nbi, fragL, Lbar, Ldt, carryV, inclV, flagsL,
                Dv, b1, b2, part, dw, db, out, lay);
            ssm_k5_reduce<<<128, 64, 0, stream>>>(part, stats + (lay + 1) * 128);
        } else {
            ssm_kl<true><<<NBLK, 512, 0, stream>>>(
                h, stats, nsc, nbi, fragL, Lbar, Ldt, carryV, inclV, flagsL,
                Dv, b1, b2, part, dw, db, out, lay);
        }
    }
}

// Round 13
// 758.869 us; speedup vs baseline: 1.5484x; 1.5484x over previous
//
#include <hip/hip_runtime.h>

#define T_LEN   131072
#define IN_DIM  256
#define HD      64
#define PD      32
#define NLAY    4
#define CHUNK   128
#define NBLK    (T_LEN / CHUNK)   // 1024
#define ASTR    68                // LDS row stride: 68 % 32 == 4 -> conflict-free column b128

typedef __attribute__((ext_vector_type(8))) short bf16x8;
typedef __attribute__((ext_vector_type(4))) float f32x4;

union FragU { uint4 q; bf16x8 v; };

__device__ __forceinline__ unsigned splitpack(float x) {
    unsigned xb = __float_as_uint(x);
    unsigned hb = (xb + 0x8000u) & 0xffff0000u;
    float lf = x - __uint_as_float(hb);
    unsigned lb = (__float_as_uint(lf) + 0x8000u) >> 16;
    return (hb >> 16) | (lb << 16);
}

__device__ __forceinline__ void packAB(float4 a0, float4 a1, bf16x8& hi, bf16x8& lo) {
    unsigned p0 = splitpack(a0.x), p1 = splitpack(a0.y);
    unsigned p2 = splitpack(a0.z), p3 = splitpack(a0.w);
    unsigned p4 = splitpack(a1.x), p5 = splitpack(a1.y);
    unsigned p6 = splitpack(a1.z), p7 = splitpack(a1.w);
    union { bf16x8 v; unsigned u[4]; } H, L;
    H.u[0] = (p0 & 0xffffu) | (p1 << 16);
    H.u[1] = (p2 & 0xffffu) | (p3 << 16);
    H.u[2] = (p4 & 0xffffu) | (p5 << 16);
    H.u[3] = (p6 & 0xffffu) | (p7 << 16);
    L.u[0] = (p0 >> 16) | (p1 & 0xffff0000u);
    L.u[1] = (p2 >> 16) | (p3 & 0xffff0000u);
    L.u[2] = (p4 >> 16) | (p5 & 0xffff0000u);
    L.u[3] = (p6 >> 16) | (p7 & 0xffff0000u);
    hi = H.v; lo = L.v;
}

#define MFMA3(ACC, AH, AL, BH, BL)                                              \
    ACC = __builtin_amdgcn_mfma_f32_16x16x32_bf16(AH, BH, ACC, 0, 0, 0);        \
    ACC = __builtin_amdgcn_mfma_f32_16x16x32_bf16(AH, BL, ACC, 0, 0, 0);        \
    ACC = __builtin_amdgcn_mfma_f32_16x16x32_bf16(AL, BH, ACC, 0, 0, 0);

__device__ __forceinline__ int kmap(int q, int j) {
    return (j < 4) ? (q * 4 + j) : (16 + q * 4 + (j - 4));
}

// ---------------------------------------------------------------- K0a: setup + zero stats/tickets
__global__ __launch_bounds__(512) void ssm_k0a(
    const float* __restrict__ Lre, const float* __restrict__ Lim,
    const float* __restrict__ logstep,
    float* __restrict__ Lbar, float* __restrict__ Ldt, float* __restrict__ stats,
    int* __restrict__ tickets)
{
    int tid = threadIdx.x;
    if (tid < NLAY * PD) {
        int l = tid >> 5, p = tid & 31;
        float dt = expf(logstep[l * PD + p]);
        float lr = Lre[l * PD + p], li = Lim[l * PD + p];
        float ldr = lr * dt, ldi = li * dt;
        Ldt[tid * 2] = ldr; Ldt[tid * 2 + 1] = ldi;
        float e = expf(ldr);
        float sn, cs; sincosf(ldi, &sn, &cs);
        Lbar[tid * 2] = e * cs; Lbar[tid * 2 + 1] = e * sn;
    }
    if (tid < NLAY * 128) stats[tid] = 0.0f;
    if (tid < 16) tickets[tid] = 0;
}

// ---------------------------------------------------------------- K0b: weight fragment builder
__global__ __launch_bounds__(256) void ssm_k0b(
    const float* __restrict__ Lre, const float* __restrict__ Lim,
    const float* __restrict__ logstep,
    const float* __restrict__ Bre, const float* __restrict__ Bim,
    const float* __restrict__ Cre, const float* __restrict__ Cim,
    const float* __restrict__ w1, const float* __restrict__ w2,
    const float* __restrict__ enc_w, const int* __restrict__ gptr,
    unsigned* __restrict__ fragE, unsigned* __restrict__ fragL)
{
    int fi = blockIdx.x * 256 + threadIdx.x;
    if (fi >= 10240) return;
    int g = gptr[0];
    int mat, lay = 0, rem;
    unsigned* outp;
    if (fi < 2048) { mat = 0; rem = fi; outp = fragE + rem * 8; }
    else {
        int t = fi - 2048;
        lay = t / 2048;
        int r2 = t % 2048;
        mat = 1 + r2 / 512;
        rem = r2 % 512;
        outp = fragL + ((size_t)(lay * 4 + (mat - 1)) * 512 + rem) * 8;
    }
    int ks = rem / 256;
    int nt = (rem / 64) & 3;
    int lane = rem & 63;
    int q = lane >> 4;
    int n = nt * 16 + (lane & 15);

    float vals[8];
#pragma unroll
    for (int j = 0; j < 8; ++j) {
        int k = ks * 32 + kmap(q, j);
        float v;
        if (mat == 0) {
            v = (n < 56) ? enc_w[(size_t)(g * 56 + n) * IN_DIM + k] : 0.0f;
        } else if (mat == 1) {
            int p = n >> 1;
            float dt = expf(logstep[lay * PD + p]);
            float lr = Lre[lay * PD + p], li = Lim[lay * PD + p];
            float e = expf(lr * dt);
            float sn, cs; sincosf(li * dt, &sn, &cs);
            float den = lr * lr + li * li;
            float nr = e * cs - 1.0f, ni = e * sn;
            float fr = (nr * lr + ni * li) / den, fimag = (ni * lr - nr * li) / den;
            float br = Bre[(lay * PD + p) * HD + k], bi = Bim[(lay * PD + p) * HD + k];
            v = (n & 1) ? (fr * bi + fimag * br) : (fr * br - fimag * bi);
        } else if (mat == 2) {
            int p = k >> 1;
            v = (k & 1) ? -Cim[((size_t)lay * HD + n) * PD + p]
                        :  Cre[((size_t)lay * HD + n) * PD + p];
        } else if (mat == 3) {
            v = w1[((size_t)lay * HD + n) * HD + k];
        } else {
            v = w2[((size_t)lay * HD + n) * HD + k];
        }
        vals[j] = v;
    }
    unsigned p8[8];
#pragma unroll
    for (int j = 0; j < 8; ++j) p8[j] = splitpack(vals[j]);
#pragma unroll
    for (int w = 0; w < 4; ++w) {
        unsigned p0 = p8[2 * w], p1 = p8[2 * w + 1];
        outp[w]     = (p0 & 0xffffu) | (p1 << 16);
        outp[4 + w] = (p0 >> 16) | (p1 & 0xffff0000u);
    }
}

// last-block stats reduce: part[128][1024] -> statsL[128], by one 512-thread block
__device__ __forceinline__ void reduce_part(const float* part, float* statsL, int tid) {
    int w = tid >> 6, lane = tid & 63;
#pragma unroll
    for (int cc = 0; cc < 16; ++cc) {
        int c = w * 16 + cc;
        float s = 0.0f;
#pragma unroll
        for (int j = 0; j < 4; ++j) {
            float4 v = *(const float4*)&part[c * 1024 + lane * 16 + j * 4];
            s += v.x + v.y + v.z + v.w;
        }
#pragma unroll
        for (int m = 1; m < 64; m <<= 1) s += __shfl_xor(s, m, 64);
        if (lane == 0) statsL[c] = s;
    }
}

// ---------------------------------------------------------------- K1: encoder (MFMA, batched loads, folded stats reduce)
__global__ __launch_bounds__(512, 4) void ssm_k1_encoder(
    const float* __restrict__ x, const int* __restrict__ gptr,
    const unsigned* __restrict__ fragE, const float* __restrict__ enc_b,
    const float* __restrict__ ctx_emb,
    float* __restrict__ h, float* __restrict__ part,
    float* __restrict__ statsL, int* __restrict__ ticket)
{
    __shared__ float sp1[512], sp2[512];
    __shared__ int isLast;
    int tid = threadIdx.x;
    int l = tid & 63, w = tid >> 6;
    int cq = l >> 4, cr = l & 15;
    int g = gptr[0];
    size_t r0 = (size_t)blockIdx.x * 128;
    int arow = 16 * w + cr;
    const float* xrow = &x[(r0 + arow) * IN_DIM];
    const f32x4 fzero = {0.f, 0.f, 0.f, 0.f};

    // issue ALL 16 x-quad loads; sched_barrier pins them before any compute
    float4 cur[16];
#pragma unroll
    for (int kt = 0; kt < 4; ++kt)
#pragma unroll
        for (int ks = 0; ks < 2; ++ks) {
            cur[kt * 4 + 2 * ks]     = *(const float4*)&xrow[kt * 64 + ks * 32 + cq * 4];
            cur[kt * 4 + 2 * ks + 1] = *(const float4*)&xrow[kt * 64 + ks * 32 + cq * 4 + 16];
        }
    __builtin_amdgcn_sched_barrier(0);

    f32x4 acc[4];
#pragma unroll
    for (int nt = 0; nt < 4; ++nt) acc[nt] = fzero;

#pragma unroll
    for (int kt = 0; kt < 4; ++kt)
#pragma unroll
        for (int ks = 0; ks < 2; ++ks) {
            bf16x8 ah, al;
            packAB(cur[kt * 4 + 2 * ks], cur[kt * 4 + 2 * ks + 1], ah, al);
            int ksg = kt * 2 + ks;
#pragma unroll
            for (int nt = 0; nt < 4; ++nt) {
                const uint4* wf = (const uint4*)&fragE[((size_t)(ksg * 4 + nt) * 64 + l) * 8];
                FragU BH, BL; BH.q = wf[0]; BL.q = wf[1];
                MFMA3(acc[nt], ah, al, BH.v, BL.v);
            }
        }
    // epilogue: bias/ctx, store h, stats partials
#pragma unroll
    for (int nt = 0; nt < 4; ++nt) {
        int ch = nt * 16 + cr;
        float eb = (ch < 56) ? enc_b[g * 56 + ch] : 0.0f;
        bool isctx = (ch >= 56);
        float cv = isctx ? ctx_emb[g * 8 + (ch - 56)] : 0.0f;
        float v1 = 0.0f, v2 = 0.0f;
#pragma unroll
        for (int r = 0; r < 4; ++r) {
            float val = isctx ? cv : (acc[nt][r] + eb);
            h[(r0 + 16 * w + 4 * cq + r) * HD + ch] = val;
            v1 += val; v2 += val * val;
        }
        v1 += __shfl_xor(v1, 16, 64); v2 += __shfl_xor(v2, 16, 64);
        v1 += __shfl_xor(v1, 32, 64); v2 += __shfl_xor(v2, 32, 64);
        if (l < 16) { sp1[w * 64 + ch] = v1; sp2[w * 64 + ch] = v2; }
    }
    __syncthreads();
    if (tid < 64) {
        float s1 = 0.0f, s2 = 0.0f;
#pragma unroll
        for (int ww = 0; ww < 8; ++ww) { s1 += sp1[ww * 64 + tid]; s2 += sp2[ww * 64 + tid]; }
        part[tid * 1024 + blockIdx.x]        = s1;
        part[(64 + tid) * 1024 + blockIdx.x] = s2;
    }
    // last block reduces part -> stats
    __syncthreads();
    if (tid == 0) {
        __threadfence();
        int old = atomicAdd(ticket, 1);
        isLast = (old == NBLK - 1);
    }
    __syncthreads();
    if (isLast) {
        __threadfence();
        reduce_part(part, statsL, tid);
    }
}

// ---------------------------------------------------------------- K2: hn -> Bu (MFMA) -> local scan -> xs; last block does carry scan
__global__ __launch_bounds__(512, 4) void ssm_k2_bu_scan(
    const float* __restrict__ h, const float* __restrict__ stats,
    const float* __restrict__ nscale, const float* __restrict__ nbias,
    const unsigned* __restrict__ fragL, const float* __restrict__ Lbar,
    const float* __restrict__ Ldt,
    float* __restrict__ xs, float* __restrict__ carry, float* __restrict__ pc,
    int* __restrict__ ticket, int lay)
{
    __shared__ __attribute__((aligned(16))) float bf[128 * ASTR];
    __shared__ float lsa[HD], lsb[HD];
    __shared__ int isLast;
    int tid = threadIdx.x;
    int l = tid & 63, w = tid >> 6;
    int cq = l >> 4, cr = l & 15;
    size_t r0 = (size_t)blockIdx.x * CHUNK;
    int arow = 16 * w + cr;
    const f32x4 fzero = {0.f, 0.f, 0.f, 0.f};

    if (tid < HD) {
        float s1 = stats[lay * 128 + tid], s2 = stats[lay * 128 + 64 + tid];
        float mu = s1 * (1.0f / T_LEN);
        float var = fmaxf(s2 * (1.0f / T_LEN) - mu * mu, 0.0f);
        float sc = nscale[lay * HD + tid] * rsqrtf(var + 1e-5f);
        lsa[tid] = sc;
        lsb[tid] = nbias[lay * HD + tid] - mu * sc;
    }
    __syncthreads();

    const float* hrowp = &h[(r0 + arow) * HD];
    const unsigned* fB = fragL + (size_t)(lay * 4 + 0) * 4096;
    f32x4 acc[4];
#pragma unroll
    for (int nt = 0; nt < 4; ++nt) acc[nt] = fzero;
#pragma unroll
    for (int ks = 0; ks < 2; ++ks) {
        int k0 = ks * 32 + cq * 4;
        float4 c0 = *(const float4*)&hrowp[k0];
        float4 c1 = *(const float4*)&hrowp[k0 + 16];
        c0.x = c0.x * lsa[k0]      + lsb[k0];
        c0.y = c0.y * lsa[k0 + 1]  + lsb[k0 + 1];
        c0.z = c0.z * lsa[k0 + 2]  + lsb[k0 + 2];
        c0.w = c0.w * lsa[k0 + 3]  + lsb[k0 + 3];
        c1.x = c1.x * lsa[k0 + 16] + lsb[k0 + 16];
        c1.y = c1.y * lsa[k0 + 17] + lsb[k0 + 17];
        c1.z = c1.z * lsa[k0 + 18] + lsb[k0 + 18];
        c1.w = c1.w * lsa[k0 + 19] + lsb[k0 + 19];
        bf16x8 ah, al;
        packAB(c0, c1, ah, al);
#pragma unroll
        for (int nt = 0; nt < 4; ++nt) {
            const uint4* wf = (const uint4*)&fB[((size_t)(ks * 4 + nt) * 64 + l) * 8];
            FragU BH, BL; BH.q = wf[0]; BL.q = wf[1];
            MFMA3(acc[nt], ah, al, BH.v, BL.v);
        }
    }
#pragma unroll
    for (int nt = 0; nt < 4; ++nt)
#pragma unroll
        for (int r = 0; r < 4; ++r)
            bf[(16 * w + 4 * cq + r) * ASTR + nt * 16 + cr] = acc[nt][r];
    __syncthreads();

    if (tid < 64) {
        int p = l >> 1;
        float Lr = Lbar[(lay * PD + p) * 2];
        float Lj = Lbar[(lay * PD + p) * 2 + 1];
        float csn = (l & 1) ? Lj : -Lj;
        float xv = 0.0f;
        for (int t = 0; t < CHUNK; ++t) {
            float b = bf[t * ASTR + l];
            float xo = __shfl_xor(xv, 1, 64);
            xv = Lr * xv + csn * xo + b;
            bf[t * ASTR + l] = xv;
        }
        carry[(size_t)blockIdx.x * 64 + l] = xv;
    }
    __syncthreads();
#pragma unroll
    for (int j = 0; j < 4; ++j) {
        float4 v = *(float4*)&bf[arow * ASTR + cq * 16 + j * 4];
        *(float4*)&xs[(r0 + arow) * HD + cq * 16 + j * 4] = v;
    }
    // ---- folded carry scan: last block does all 32 p's (4 per wave)
    if (tid == 0) {
        __threadfence();
        int old = atomicAdd(ticket, 1);
        isLast = (old == NBLK - 1);
    }
    __syncthreads();
    if (isLast) {
        __threadfence();
        int lane = l;
#pragma unroll
        for (int pp = 0; pp < 4; ++pp) {
            int p = w * 4 + pp;
            float ldr = Ldt[lay * 64 + 2 * p], ldi = Ldt[lay * 64 + 2 * p + 1];
            float er = __expf(ldr * (float)CHUNK);
            float an = ldi * (float)CHUNK;
            float lcr = er * __cosf(an), lci = er * __sinf(an);
            float crv[16], civ[16];
#pragma unroll
            for (int j = 0; j < 16; ++j) {
                crv[j] = carry[(size_t)(lane * 16 + j) * 64 + 2 * p];
                civ[j] = carry[(size_t)(lane * 16 + j) * 64 + 2 * p + 1];
            }
            float ur = 0.0f, ui = 0.0f;
#pragma unroll
            for (int j = 0; j < 16; ++j) {
                float nr = lcr * ur - lci * ui + crv[j];
                float ni = lcr * ui + lci * ur + civ[j];
                ur = nr; ui = ni;
            }
            float mr = lcr, mi = lci;
#pragma unroll
            for (int s = 0; s < 4; ++s) { float t = mr * mr - mi * mi; mi = 2.0f * mr * mi; mr = t; }
#pragma unroll
            for (int d = 1; d < 64; d <<= 1) {
                float tr = __shfl_up(ur, d, 64);
                float ti = __shfl_up(ui, d, 64);
                if (lane >= d) { ur = mr * tr - mi * ti + ur; ui = mr * ti + mi * tr + ui; }
                float t = mr * mr - mi * mi; mi = 2.0f * mr * mi; mr = t;
            }
            float pr = __shfl_up(ur, 1, 64), pi = __shfl_up(ui, 1, 64);
            float xr = (lane == 0) ? 0.0f : pr;
            float xi = (lane == 0) ? 0.0f : pi;
#pragma unroll
            for (int j = 0; j < 16; ++j) {
                pc[(size_t)(lane * 16 + j) * 64 + 2 * p]     = xr;
                pc[(size_t)(lane * 16 + j) * 64 + 2 * p + 1] = xi;
                float nr = lcr * xr - lci * xi + crv[j];
                float ni = lcr * xi + lci * xr + civ[j];
                xr = nr; xi = ni;
            }
        }
    }
}

// ---------------------------------------------------------------- K4: fixup + C-proj + gelu + GLU + residual (MFMA); folded stats reduce
template <bool LAST>
__global__ __launch_bounds__(512, 4) void ssm_k4_out(
    const float* __restrict__ h, const float* __restrict__ xs,
    const float* __restrict__ pc, const float* __restrict__ stats,
    const float* __restrict__ nscale, const float* __restrict__ nbias,
    const float* __restrict__ Ldt, const unsigned* __restrict__ fragL,
    const float* __restrict__ Dv,
    const float* __restrict__ b1, const float* __restrict__ b2,
    float* __restrict__ hout, float* __restrict__ part,
    float* __restrict__ stats_next, int* __restrict__ ticket,
    const float* __restrict__ dec_w, const float* __restrict__ dec_b,
    float* __restrict__ outp, int lay)
{
    __shared__ __attribute__((aligned(16))) unsigned act[128 * ASTR];
    __shared__ float lsa[HD], lsb[HD], lsd[HD], lpc[HD], lld[HD];
    __shared__ float sp1[512], sp2[512];
    __shared__ int isLast;
    int tid = threadIdx.x;
    int l = tid & 63, w = tid >> 6;
    int cq = l >> 4, cr = l & 15;
    size_t r0 = (size_t)blockIdx.x * CHUNK;
    int arow = 16 * w + cr;
    const f32x4 fzero = {0.f, 0.f, 0.f, 0.f};

    if (tid < HD) {
        float s1 = stats[lay * 128 + tid], s2 = stats[lay * 128 + 64 + tid];
        float mu = s1 * (1.0f / T_LEN);
        float var = fmaxf(s2 * (1.0f / T_LEN) - mu * mu, 0.0f);
        float sc = nscale[lay * HD + tid] * rsqrtf(var + 1e-5f);
        lsa[tid] = sc;
        lsb[tid] = nbias[lay * HD + tid] - mu * sc;
        lsd[tid] = Dv[lay * HD + tid];
        lpc[tid] = pc[(size_t)blockIdx.x * 64 + tid];
        lld[tid] = Ldt[lay * 64 + tid];
    }
    __syncthreads();

    const unsigned* fC = fragL + (size_t)(lay * 4 + 1) * 4096;
    f32x4 yacc[4];
#pragma unroll
    for (int nt = 0; nt < 4; ++nt) yacc[nt] = fzero;
    {
        const float* xrowp = &xs[(r0 + arow) * HD];
        float tt = (float)(arow + 1);
#pragma unroll
        for (int ks = 0; ks < 2; ++ks) {
            int k0 = ks * 32 + cq * 4;
            float4 v0 = *(const float4*)&xrowp[k0];
            float4 v1 = *(const float4*)&xrowp[k0 + 16];
            {
                float e1 = __expf(lld[k0] * tt), an = lld[k0 + 1] * tt;
                float prr = e1 * __cosf(an), pri = e1 * __sinf(an);
                v0.x += prr * lpc[k0] - pri * lpc[k0 + 1];
                v0.y += prr * lpc[k0 + 1] + pri * lpc[k0];
            }
            {
                float e1 = __expf(lld[k0 + 2] * tt), an = lld[k0 + 3] * tt;
                float prr = e1 * __cosf(an), pri = e1 * __sinf(an);
                v0.z += prr * lpc[k0 + 2] - pri * lpc[k0 + 3];
                v0.w += prr * lpc[k0 + 3] + pri * lpc[k0 + 2];
            }
            {
                float e1 = __expf(lld[k0 + 16] * tt), an = lld[k0 + 17] * tt;
                float prr = e1 * __cosf(an), pri = e1 * __sinf(an);
                v1.x += prr * lpc[k0 + 16] - pri * lpc[k0 + 17];
                v1.y += prr * lpc[k0 + 17] + pri * lpc[k0 + 16];
            }
            {
                float e1 = __expf(lld[k0 + 18] * tt), an = lld[k0 + 19] * tt;
                float prr = e1 * __cosf(an), pri = e1 * __sinf(an);
                v1.z += prr * lpc[k0 + 18] - pri * lpc[k0 + 19];
                v1.w += prr * lpc[k0 + 19] + pri * lpc[k0 + 18];
            }
            bf16x8 ah, al;
            packAB(v0, v1, ah, al);
#pragma unroll
            for (int nt = 0; nt < 4; ++nt) {
                const uint4* wf = (const uint4*)&fC[((size_t)(ks * 4 + nt) * 64 + l) * 8];
                FragU BH, BL; BH.q = wf[0]; BL.q = wf[1];
                MFMA3(yacc[nt], ah, al, BH.v, BL.v);
            }
        }
    }

    float hrow[16];
#pragma unroll
    for (int nt = 0; nt < 4; ++nt) {
        int ch = nt * 16 + cr;
        float sav = lsa[ch], sbv = lsb[ch], dvv = lsd[ch];
#pragma unroll
        for (int r = 0; r < 4; ++r) {
            int row = 16 * w + 4 * cq + r;
            float hv = h[(r0 + row) * HD + ch];
            hrow[nt * 4 + r] = hv;
            float t = 2.0f * yacc[nt][r] + (hv * sav + sbv) * dvv;
            float u2 = 1.5957691216057308f * (t + 0.044715f * t * t * t);
            float gv = t / (1.0f + __expf(-u2));
            act[row * ASTR + ch] = splitpack(gv);
        }
    }
    asm volatile("s_waitcnt lgkmcnt(0)" ::: "memory");

    const unsigned* f1 = fragL + (size_t)(lay * 4 + 2) * 4096;
    const unsigned* f2 = fragL + (size_t)(lay * 4 + 3) * 4096;
    f32x4 uacc[4], sacc[4];
#pragma unroll
    for (int nt = 0; nt < 4; ++nt) { uacc[nt] = fzero; sacc[nt] = fzero; }
#pragma unroll
    for (int ks = 0; ks < 2; ++ks) {
        int col = ks * 32 + 4 * cq;
        uint4 a0 = *(const uint4*)&act[arow * ASTR + col];
        uint4 a1 = *(const uint4*)&act[arow * ASTR + col + 16];
        union { bf16x8 v; unsigned u[4]; } H, L;
        H.u[0] = (a0.x & 0xffffu) | (a0.y << 16);
        H.u[1] = (a0.z & 0xffffu) | (a0.w << 16);
        H.u[2] = (a1.x & 0xffffu) | (a1.y << 16);
        H.u[3] = (a1.z & 0xffffu) | (a1.w << 16);
        L.u[0] = (a0.x >> 16) | (a0.y & 0xffff0000u);
        L.u[1] = (a0.z >> 16) | (a0.w & 0xffff0000u);
        L.u[2] = (a1.x >> 16) | (a1.y & 0xffff0000u);
        L.u[3] = (a1.z >> 16) | (a1.w & 0xffff0000u);
#pragma unroll
        for (int nt = 0; nt < 4; ++nt) {
            const uint4* w1f = (const uint4*)&f1[((size_t)(ks * 4 + nt) * 64 + l) * 8];
            FragU BH1, BL1; BH1.q = w1f[0]; BL1.q = w1f[1];
            MFMA3(uacc[nt], H.v, L.v, BH1.v, BL1.v);
            const uint4* w2f = (const uint4*)&f2[((size_t)(ks * 4 + nt) * 64 + l) * 8];
            FragU BH2, BL2; BH2.q = w2f[0]; BL2.q = w2f[1];
            MFMA3(sacc[nt], H.v, L.v, BH2.v, BL2.v);
        }
    }

    if (LAST) {
        float o0[4] = {0.f, 0.f, 0.f, 0.f}, o1[4] = {0.f, 0.f, 0.f, 0.f};
#pragma unroll
        for (int nt = 0; nt < 4; ++nt) {
            int ch = nt * 16 + cr;
            float bb1 = b1[lay * HD + ch], bb2 = b2[lay * HD + ch];
            float dw0 = dec_w[ch], dw1 = dec_w[64 + ch];
#pragma unroll
            for (int r = 0; r < 4; ++r) {
                float sv = sacc[nt][r] + bb2;
                float sg = 1.0f / (1.0f + __expf(-sv));
                float ho = hrow[nt * 4 + r] + (uacc[nt][r] + bb1) * sg;
                o0[r] += ho * dw0;
                o1[r] += ho * dw1;
            }
        }
#pragma unroll
        for (int r = 0; r < 4; ++r) {
#pragma unroll
            for (int m = 1; m < 16; m <<= 1) {
                o0[r] += __shfl_xor(o0[r], m, 64);
                o1[r] += __shfl_xor(o1[r], m, 64);
            }
        }
        if (cr == 0) {
            float db0 = dec_b[0], db1 = dec_b[1];
#pragma unroll
            for (int r = 0; r < 4; ++r) {
                int row = 16 * w + 4 * cq + r;
                *(float2*)&outp[(r0 + row) * 2] = make_float2(o0[r] + db0, o1[r] + db1);
            }
        }
    } else {
#pragma unroll
        for (int nt = 0; nt < 4; ++nt) {
            int ch = nt * 16 + cr;
            float bb1 = b1[lay * HD + ch], bb2 = b2[lay * HD + ch];
            float v1 = 0.0f, v2 = 0.0f;
#pragma unroll
            for (int r = 0; r < 4; ++r) {
                int row = 16 * w + 4 * cq + r;
                float sv = sacc[nt][r] + bb2;
                float sg = 1.0f / (1.0f + __expf(-sv));
                float ho = hrow[nt * 4 + r] + (uacc[nt][r] + bb1) * sg;
                hout[(r0 + row) * HD + ch] = ho;
                v1 += ho; v2 += ho * ho;
            }
            v1 += __shfl_xor(v1, 16, 64); v2 += __shfl_xor(v2, 16, 64);
            v1 += __shfl_xor(v1, 32, 64); v2 += __shfl_xor(v2, 32, 64);
            if (l < 16) { sp1[w * 64 + ch] = v1; sp2[w * 64 + ch] = v2; }
        }
        __syncthreads();
        if (tid < 64) {
            float s1 = 0.0f, s2 = 0.0f;
#pragma unroll
            for (int ww = 0; ww < 8; ++ww) { s1 += sp1[ww * 64 + tid]; s2 += sp2[ww * 64 + tid]; }
            part[tid * 1024 + blockIdx.x]        = s1;
            part[(64 + tid) * 1024 + blockIdx.x] = s2;
        }
        __syncthreads();
        if (tid == 0) {
            __threadfence();
            int old = atomicAdd(ticket, 1);
            isLast = (old == NBLK - 1);
        }
        __syncthreads();
        if (isLast) {
            __threadfence();
            reduce_part(part, stats_next, tid);
        }
    }
}

// ---------------------------------------------------------------- launch
extern "C" void kernel_launch(void* const* d_in, const int* in_sizes, int n_in,
                              void* d_out, int out_size, void* d_ws, size_t ws_size,
                              hipStream_t stream)
{
    (void)in_sizes; (void)n_in; (void)out_size; (void)ws_size;
    const float* x     = (const float*)d_in[0];
    const int*   gidx  = (const int*)d_in[1];
    const float* enc_w = (const float*)d_in[2];
    const float* enc_b = (const float*)d_in[3];
    const float* ctx   = (const float*)d_in[4];
    const float* Lre   = (const float*)d_in[5];
    const float* Lim   = (const float*)d_in[6];
    const float* Bre   = (const float*)d_in[7];
    const float* Bim   = (const float*)d_in[8];
    const float* Cre   = (const float*)d_in[9];
    const float* Cim   = (const float*)d_in[10];
    const float* Dv    = (const float*)d_in[11];
    const float* lstep = (const float*)d_in[12];
    const float* nsc   = (const float*)d_in[13];
    const float* nbi   = (const float*)d_in[14];
    const float* w1    = (const float*)d_in[15];
    const float* b1    = (const float*)d_in[16];
    const float* w2    = (const float*)d_in[17];
    const float* b2    = (const float*)d_in[18];
    const float* dw    = (const float*)d_in[19];
    const float* db    = (const float*)d_in[20];
    float* out = (float*)d_out;

    float* ws = (float*)d_ws;
    float* h     = ws;  ws += (size_t)T_LEN * HD;
    float* xs    = ws;  ws += (size_t)T_LEN * HD;
    float* carry = ws;  ws += (size_t)NBLK * HD;
    float* pc    = ws;  ws += (size_t)NBLK * HD;
    float* stats = ws;  ws += NLAY * 128;
    float* Lbar  = ws;  ws += NLAY * PD * 2;
    float* Ldt   = ws;  ws += NLAY * PD * 2;
    int* tickets = (int*)ws;  ws += 16;
    unsigned* fragE = (unsigned*)ws;  ws += 16384;
    unsigned* fragL = (unsigned*)ws;  ws += 65536;
    float* part  = ws;  ws += 128 * 1024;

    ssm_k0a<<<1, 512, 0, stream>>>(Lre, Lim, lstep, Lbar, Ldt, stats, tickets);
    ssm_k0b<<<40, 256, 0, stream>>>(Lre, Lim, lstep, Bre, Bim, Cre, Cim, w1, w2,
                                    enc_w, gidx, fragE, fragL);
    ssm_k1_encoder<<<1024, 512, 0, stream>>>(x, gidx, fragE, enc_b, ctx, h, part,
                                             stats, &tickets[15]);
    for (int lay = 0; lay < NLAY; ++lay) {
        ssm_k2_bu_scan<<<NBLK, 512, 0, stream>>>(h, stats, nsc, nbi, fragL, Lbar, Ldt,
                                                 xs, carry, pc, &tickets[lay], lay);
        if (lay < NLAY - 1) {
            ssm_k4_out<false><<<NBLK, 512, 0, stream>>>(
                h, xs, pc, stats, nsc, nbi, Ldt, fragL, Dv, b1, b2,
                h, part, stats + (lay + 1) * 128, &tickets[4 + lay], dw, db, out, lay);
        } else {
            ssm_k4_out<true><<<NBLK, 512, 0, stream>>>(
                h, xs, pc, stats, nsc, nbi, Ldt, fragL, Dv, b1, b2,
                h, part, stats, &tickets[8], dw, db, out, lay);
        }
    }
}

// Round 14
// 345.658 us; speedup vs baseline: 3.3993x; 2.1954x over previous
//
#include <hip/hip_runtime.h>

#define T_LEN   131072
#define IN_DIM  256
#define HD      64
#define PD      32
#define NLAY    4
#define CHUNK   128
#define NBLK    (T_LEN / CHUNK)   // 1024
#define ASTR    68                // LDS row stride: 68 % 32 == 4 -> conflict-free column b128

typedef __attribute__((ext_vector_type(8))) short bf16x8;
typedef __attribute__((ext_vector_type(4))) float f32x4;

union FragU { uint4 q; bf16x8 v; };

__device__ __forceinline__ unsigned splitpack(float x) {
    unsigned xb = __float_as_uint(x);
    unsigned hb = (xb + 0x8000u) & 0xffff0000u;
    float lf = x - __uint_as_float(hb);
    unsigned lb = (__float_as_uint(lf) + 0x8000u) >> 16;
    return (hb >> 16) | (lb << 16);
}

__device__ __forceinline__ void packAB(float4 a0, float4 a1, bf16x8& hi, bf16x8& lo) {
    unsigned p0 = splitpack(a0.x), p1 = splitpack(a0.y);
    unsigned p2 = splitpack(a0.z), p3 = splitpack(a0.w);
    unsigned p4 = splitpack(a1.x), p5 = splitpack(a1.y);
    unsigned p6 = splitpack(a1.z), p7 = splitpack(a1.w);
    union { bf16x8 v; unsigned u[4]; } H, L;
    H.u[0] = (p0 & 0xffffu) | (p1 << 16);
    H.u[1] = (p2 & 0xffffu) | (p3 << 16);
    H.u[2] = (p4 & 0xffffu) | (p5 << 16);
    H.u[3] = (p6 & 0xffffu) | (p7 << 16);
    L.u[0] = (p0 >> 16) | (p1 & 0xffff0000u);
    L.u[1] = (p2 >> 16) | (p3 & 0xffff0000u);
    L.u[2] = (p4 >> 16) | (p5 & 0xffff0000u);
    L.u[3] = (p6 >> 16) | (p7 & 0xffff0000u);
    hi = H.v; lo = L.v;
}

#define MFMA3(ACC, AH, AL, BH, BL)                                              \
    ACC = __builtin_amdgcn_mfma_f32_16x16x32_bf16(AH, BH, ACC, 0, 0, 0);        \
    ACC = __builtin_amdgcn_mfma_f32_16x16x32_bf16(AH, BL, ACC, 0, 0, 0);        \
    ACC = __builtin_amdgcn_mfma_f32_16x16x32_bf16(AL, BH, ACC, 0, 0, 0);

__device__ __forceinline__ int kmap(int q, int j) {
    return (j < 4) ? (q * 4 + j) : (16 + q * 4 + (j - 4));
}

// ---------------------------------------------------------------- K0a
__global__ __launch_bounds__(512) void ssm_k0a(
    const float* __restrict__ Lre, const float* __restrict__ Lim,
    const float* __restrict__ logstep,
    float* __restrict__ Lbar, float* __restrict__ Ldt, float* __restrict__ stats)
{
    int tid = threadIdx.x;
    if (tid < NLAY * PD) {
        int l = tid >> 5, p = tid & 31;
        float dt = expf(logstep[l * PD + p]);
        float lr = Lre[l * PD + p], li = Lim[l * PD + p];
        float ldr = lr * dt, ldi = li * dt;
        Ldt[tid * 2] = ldr; Ldt[tid * 2 + 1] = ldi;
        float e = expf(ldr);
        float sn, cs; sincosf(ldi, &sn, &cs);
        Lbar[tid * 2] = e * cs; Lbar[tid * 2 + 1] = e * sn;
    }
    if (tid < NLAY * 128) stats[tid] = 0.0f;
}

// ---------------------------------------------------------------- K0b: weight fragment builder
__global__ __launch_bounds__(256) void ssm_k0b(
    const float* __restrict__ Lre, const float* __restrict__ Lim,
    const float* __restrict__ logstep,
    const float* __restrict__ Bre, const float* __restrict__ Bim,
    const float* __restrict__ Cre, const float* __restrict__ Cim,
    const float* __restrict__ w1, const float* __restrict__ w2,
    const float* __restrict__ enc_w, const int* __restrict__ gptr,
    unsigned* __restrict__ fragE, unsigned* __restrict__ fragL)
{
    int fi = blockIdx.x * 256 + threadIdx.x;   // 0..10239
    if (fi >= 10240) return;
    int g = gptr[0];
    int mat, lay = 0, rem;
    unsigned* outp;
    if (fi < 2048) { mat = 0; rem = fi; outp = fragE + rem * 8; }
    else {
        int t = fi - 2048;
        lay = t / 2048;
        int r2 = t % 2048;
        mat = 1 + r2 / 512;
        rem = r2 % 512;
        outp = fragL + ((size_t)(lay * 4 + (mat - 1)) * 512 + rem) * 8;
    }
    int ks = rem / 256;
    int nt = (rem / 64) & 3;
    int lane = rem & 63;
    int q = lane >> 4;
    int n = nt * 16 + (lane & 15);

    float vals[8];
#pragma unroll
    for (int j = 0; j < 8; ++j) {
        int k = ks * 32 + kmap(q, j);
        float v;
        if (mat == 0) {
            v = (n < 56) ? enc_w[(size_t)(g * 56 + n) * IN_DIM + k] : 0.0f;
        } else if (mat == 1) {
            int p = n >> 1;
            float dt = expf(logstep[lay * PD + p]);
            float lr = Lre[lay * PD + p], li = Lim[lay * PD + p];
            float e = expf(lr * dt);
            float sn, cs; sincosf(li * dt, &sn, &cs);
            float den = lr * lr + li * li;
            float nr = e * cs - 1.0f, ni = e * sn;
            float fr = (nr * lr + ni * li) / den, fimag = (ni * lr - nr * li) / den;
            float br = Bre[(lay * PD + p) * HD + k], bi = Bim[(lay * PD + p) * HD + k];
            v = (n & 1) ? (fr * bi + fimag * br) : (fr * br - fimag * bi);
        } else if (mat == 2) {
            int p = k >> 1;
            v = (k & 1) ? -Cim[((size_t)lay * HD + n) * PD + p]
                        :  Cre[((size_t)lay * HD + n) * PD + p];
        } else if (mat == 3) {
            v = w1[((size_t)lay * HD + n) * HD + k];
        } else {
            v = w2[((size_t)lay * HD + n) * HD + k];
        }
        vals[j] = v;
    }
    unsigned p8[8];
#pragma unroll
    for (int j = 0; j < 8; ++j) p8[j] = splitpack(vals[j]);
#pragma unroll
    for (int w = 0; w < 4; ++w) {
        unsigned p0 = p8[2 * w], p1 = p8[2 * w + 1];
        outp[w]     = (p0 & 0xffffu) | (p1 << 16);
        outp[4 + w] = (p0 >> 16) | (p1 & 0xffff0000u);
    }
}

// ---------------------------------------------------------------- K5: stats partial reduce
__global__ __launch_bounds__(64) void ssm_k5_reduce(
    const float* __restrict__ part, float* __restrict__ statsL)
{
    int c = blockIdx.x;
    int lane = threadIdx.x;
    float s = 0.0f;
#pragma unroll
    for (int j = 0; j < 4; ++j) {
        float4 v = *(const float4*)&part[c * 1024 + j * 256 + lane * 4];
        s += v.x + v.y + v.z + v.w;
    }
#pragma unroll
    for (int m = 1; m < 64; m <<= 1) s += __shfl_xor(s, m, 64);
    if (lane == 0) statsL[c] = s;
}

// ---------------------------------------------------------------- K1: encoder (MFMA, batched loads)
__global__ __launch_bounds__(512, 4) void ssm_k1_encoder(
    const float* __restrict__ x, const int* __restrict__ gptr,
    const unsigned* __restrict__ fragE, const float* __restrict__ enc_b,
    const float* __restrict__ ctx_emb,
    float* __restrict__ h, float* __restrict__ part)
{
    __shared__ float sp1[512], sp2[512];
    int tid = threadIdx.x;
    int l = tid & 63, w = tid >> 6;
    int cq = l >> 4, cr = l & 15;
    int g = gptr[0];
    size_t r0 = (size_t)blockIdx.x * 128;
    int arow = 16 * w + cr;
    const float* xrow = &x[(r0 + arow) * IN_DIM];
    const f32x4 fzero = {0.f, 0.f, 0.f, 0.f};

    // issue ALL 16 x-quad loads; sched_barrier pins them before any compute
    float4 cur[16];
#pragma unroll
    for (int kt = 0; kt < 4; ++kt)
#pragma unroll
        for (int ks = 0; ks < 2; ++ks) {
            cur[kt * 4 + 2 * ks]     = *(const float4*)&xrow[kt * 64 + ks * 32 + cq * 4];
            cur[kt * 4 + 2 * ks + 1] = *(const float4*)&xrow[kt * 64 + ks * 32 + cq * 4 + 16];
        }
    __builtin_amdgcn_sched_barrier(0);

    f32x4 acc[4];
#pragma unroll
    for (int nt = 0; nt < 4; ++nt) acc[nt] = fzero;

#pragma unroll
    for (int kt = 0; kt < 4; ++kt)
#pragma unroll
        for (int ks = 0; ks < 2; ++ks) {
            bf16x8 ah, al;
            packAB(cur[kt * 4 + 2 * ks], cur[kt * 4 + 2 * ks + 1], ah, al);
            int ksg = kt * 2 + ks;
#pragma unroll
            for (int nt = 0; nt < 4; ++nt) {
                const uint4* wf = (const uint4*)&fragE[((size_t)(ksg * 4 + nt) * 64 + l) * 8];
                FragU BH, BL; BH.q = wf[0]; BL.q = wf[1];
                MFMA3(acc[nt], ah, al, BH.v, BL.v);
            }
        }
    // epilogue: bias/ctx, store h, stats partials
#pragma unroll
    for (int nt = 0; nt < 4; ++nt) {
        int ch = nt * 16 + cr;
        float eb = (ch < 56) ? enc_b[g * 56 + ch] : 0.0f;
        bool isctx = (ch >= 56);
        float cv = isctx ? ctx_emb[g * 8 + (ch - 56)] : 0.0f;
        float v1 = 0.0f, v2 = 0.0f;
#pragma unroll
        for (int r = 0; r < 4; ++r) {
            float val = isctx ? cv : (acc[nt][r] + eb);
            h[(r0 + 16 * w + 4 * cq + r) * HD + ch] = val;
            v1 += val; v2 += val * val;
        }
        v1 += __shfl_xor(v1, 16, 64); v2 += __shfl_xor(v2, 16, 64);
        v1 += __shfl_xor(v1, 32, 64); v2 += __shfl_xor(v2, 32, 64);
        if (l < 16) { sp1[w * 64 + ch] = v1; sp2[w * 64 + ch] = v2; }
    }
    __syncthreads();
    if (tid < 64) {
        float s1 = 0.0f, s2 = 0.0f;
#pragma unroll
        for (int ww = 0; ww < 8; ++ww) { s1 += sp1[ww * 64 + tid]; s2 += sp2[ww * 64 + tid]; }
        part[tid * 1024 + blockIdx.x]        = s1;   // no atomics: block owns its column
        part[(64 + tid) * 1024 + blockIdx.x] = s2;
    }
}

// ---------------------------------------------------------------- K2: hn -> Bu (MFMA direct) -> local scan
__global__ __launch_bounds__(512, 4) void ssm_k2_bu_scan(
    const float* __restrict__ h, const float* __restrict__ stats,
    const float* __restrict__ nscale, const float* __restrict__ nbias,
    const unsigned* __restrict__ fragL, const float* __restrict__ Lbar,
    float* __restrict__ xs, float* __restrict__ carry, int lay)
{
    __shared__ __attribute__((aligned(16))) float bf[128 * ASTR];
    __shared__ float lsa[HD], lsb[HD];
    int tid = threadIdx.x;
    int l = tid & 63, w = tid >> 6;
    int cq = l >> 4, cr = l & 15;
    size_t r0 = (size_t)blockIdx.x * CHUNK;
    int arow = 16 * w + cr;
    const f32x4 fzero = {0.f, 0.f, 0.f, 0.f};

    // hoist raw h loads before LDS setup: latency hides under barrier
    const float* hrowp = &h[(r0 + arow) * HD];
    float4 hq[4];
#pragma unroll
    for (int ks = 0; ks < 2; ++ks) {
        int k0 = ks * 32 + cq * 4;
        hq[2 * ks]     = *(const float4*)&hrowp[k0];
        hq[2 * ks + 1] = *(const float4*)&hrowp[k0 + 16];
    }

    if (tid < HD) {
        float s1 = stats[lay * 128 + tid], s2 = stats[lay * 128 + 64 + tid];
        float mu = s1 * (1.0f / T_LEN);
        float var = fmaxf(s2 * (1.0f / T_LEN) - mu * mu, 0.0f);
        float sc = nscale[lay * HD + tid] * rsqrtf(var + 1e-5f);
        lsa[tid] = sc;
        lsb[tid] = nbias[lay * HD + tid] - mu * sc;
    }
    __syncthreads();

    const unsigned* fB = fragL + (size_t)(lay * 4 + 0) * 4096;
    f32x4 acc[4];
#pragma unroll
    for (int nt = 0; nt < 4; ++nt) acc[nt] = fzero;
#pragma unroll
    for (int ks = 0; ks < 2; ++ks) {
        int k0 = ks * 32 + cq * 4;
        float4 c0 = hq[2 * ks];
        float4 c1 = hq[2 * ks + 1];
        c0.x = c0.x * lsa[k0]      + lsb[k0];
        c0.y = c0.y * lsa[k0 + 1]  + lsb[k0 + 1];
        c0.z = c0.z * lsa[k0 + 2]  + lsb[k0 + 2];
        c0.w = c0.w * lsa[k0 + 3]  + lsb[k0 + 3];
        c1.x = c1.x * lsa[k0 + 16] + lsb[k0 + 16];
        c1.y = c1.y * lsa[k0 + 17] + lsb[k0 + 17];
        c1.z = c1.z * lsa[k0 + 18] + lsb[k0 + 18];
        c1.w = c1.w * lsa[k0 + 19] + lsb[k0 + 19];
        bf16x8 ah, al;
        packAB(c0, c1, ah, al);
#pragma unroll
        for (int nt = 0; nt < 4; ++nt) {
            const uint4* wf = (const uint4*)&fB[((size_t)(ks * 4 + nt) * 64 + l) * 8];
            FragU BH, BL; BH.q = wf[0]; BL.q = wf[1];
            MFMA3(acc[nt], ah, al, BH.v, BL.v);
        }
    }
    // Bu -> LDS (C/D layout)
#pragma unroll
    for (int nt = 0; nt < 4; ++nt)
#pragma unroll
        for (int r = 0; r < 4; ++r)
            bf[(16 * w + 4 * cq + r) * ASTR + nt * 16 + cr] = acc[nt][r];
    __syncthreads();

    // in-chunk scan: wave 0
    if (tid < 64) {
        int p = l >> 1;
        float Lr = Lbar[(lay * PD + p) * 2];
        float Lj = Lbar[(lay * PD + p) * 2 + 1];
        float csn = (l & 1) ? Lj : -Lj;
        float xv = 0.0f;
        for (int t = 0; t < CHUNK; ++t) {
            float b = bf[t * ASTR + l];
            float xo = __shfl_xor(xv, 1, 64);
            xv = Lr * xv + csn * xo + b;
            bf[t * ASTR + l] = xv;
        }
        carry[(size_t)blockIdx.x * 64 + l] = xv;
    }
    __syncthreads();
#pragma unroll
    for (int j = 0; j < 4; ++j) {
        float4 v = *(float4*)&bf[arow * ASTR + cq * 16 + j * 4];
        *(float4*)&xs[(r0 + arow) * HD + cq * 16 + j * 4] = v;
    }
}

// ---------------------------------------------------------------- K3: cross-chunk carry scan
__global__ __launch_bounds__(64) void ssm_k3_carry(
    const float* __restrict__ carry, const float* __restrict__ Ldt,
    float* __restrict__ pc, int lay)
{
    int p = blockIdx.x;
    int lane = threadIdx.x;
    float ldr = Ldt[(lay * PD + p) * 2], ldi = Ldt[(lay * PD + p) * 2 + 1];
    float er = __expf(ldr * (float)CHUNK);
    float an = ldi * (float)CHUNK;
    float lcr = er * __cosf(an), lci = er * __sinf(an);
    float cr[16], ci[16];
#pragma unroll
    for (int j = 0; j < 16; ++j) {
        cr[j] = carry[(size_t)(lane * 16 + j) * 64 + 2 * p];
        ci[j] = carry[(size_t)(lane * 16 + j) * 64 + 2 * p + 1];
    }
    float ur = 0.0f, ui = 0.0f;
#pragma unroll
    for (int j = 0; j < 16; ++j) {
        float nr = lcr * ur - lci * ui + cr[j];
        float ni = lcr * ui + lci * ur + ci[j];
        ur = nr; ui = ni;
    }
    float mr = lcr, mi = lci;
#pragma unroll
    for (int s = 0; s < 4; ++s) { float t = mr * mr - mi * mi; mi = 2.0f * mr * mi; mr = t; }
#pragma unroll
    for (int d = 1; d < 64; d <<= 1) {
        float tr = __shfl_up(ur, d, 64);
        float ti = __shfl_up(ui, d, 64);
        if (lane >= d) { ur = mr * tr - mi * ti + ur; ui = mr * ti + mi * tr + ui; }
        float t = mr * mr - mi * mi; mi = 2.0f * mr * mi; mr = t;
    }
    float pr = __shfl_up(ur, 1, 64), pi = __shfl_up(ui, 1, 64);
    float xr = (lane == 0) ? 0.0f : pr;
    float xi = (lane == 0) ? 0.0f : pi;
#pragma unroll
    for (int j = 0; j < 16; ++j) {
        pc[(size_t)(lane * 16 + j) * 64 + 2 * p]     = xr;
        pc[(size_t)(lane * 16 + j) * 64 + 2 * p + 1] = xi;
        float nr = lcr * xr - lci * xi + cr[j];
        float ni = lcr * xi + lci * xr + ci[j];
        xr = nr; xi = ni;
    }
}

// ---------------------------------------------------------------- K4: fixup + C-proj + gelu + GLU + residual (MFMA)
template <bool LAST>
__global__ __launch_bounds__(512, 4) void ssm_k4_out(
    const float* __restrict__ h, const float* __restrict__ xs,
    const float* __restrict__ pc, const float* __restrict__ stats,
    const float* __restrict__ nscale, const float* __restrict__ nbias,
    const float* __restrict__ Ldt, const unsigned* __restrict__ fragL,
    const float* __restrict__ Dv,
    const float* __restrict__ b1, const float* __restrict__ b2,
    float* __restrict__ hout, float* __restrict__ part,
    const float* __restrict__ dec_w, const float* __restrict__ dec_b,
    float* __restrict__ outp, int lay)
{
    __shared__ __attribute__((aligned(16))) unsigned act[128 * ASTR];
    __shared__ float lsa[HD], lsb[HD], lsd[HD], lpc[HD], lld[HD];
    __shared__ float sp1[512], sp2[512];
    int tid = threadIdx.x;
    int l = tid & 63, w = tid >> 6;
    int cq = l >> 4, cr = l & 15;
    size_t r0 = (size_t)blockIdx.x * CHUNK;
    int arow = 16 * w + cr;
    const f32x4 fzero = {0.f, 0.f, 0.f, 0.f};

    // hoist ALL xs + h global loads to the top (latency hides under barrier + C-proj)
    float4 xq[4];
    {
        const float* xrowp = &xs[(r0 + arow) * HD];
#pragma unroll
        for (int ks = 0; ks < 2; ++ks) {
            int k0 = ks * 32 + cq * 4;
            xq[2 * ks]     = *(const float4*)&xrowp[k0];
            xq[2 * ks + 1] = *(const float4*)&xrowp[k0 + 16];
        }
    }
    float hrow[16];
#pragma unroll
    for (int nt = 0; nt < 4; ++nt) {
        int ch = nt * 16 + cr;
#pragma unroll
        for (int r = 0; r < 4; ++r)
            hrow[nt * 4 + r] = h[(r0 + 16 * w + 4 * cq + r) * HD + ch];
    }

    if (tid < HD) {
        float s1 = stats[lay * 128 + tid], s2 = stats[lay * 128 + 64 + tid];
        float mu = s1 * (1.0f / T_LEN);
        float var = fmaxf(s2 * (1.0f / T_LEN) - mu * mu, 0.0f);
        float sc = nscale[lay * HD + tid] * rsqrtf(var + 1e-5f);
        lsa[tid] = sc;
        lsb[tid] = nbias[lay * HD + tid] - mu * sc;
        lsd[tid] = Dv[lay * HD + tid];
        lpc[tid] = pc[(size_t)blockIdx.x * 64 + tid];
        lld[tid] = Ldt[lay * 64 + tid];
    }
    __syncthreads();

    // fixup (regs) + C-proj GEMM
    const unsigned* fC = fragL + (size_t)(lay * 4 + 1) * 4096;
    f32x4 yacc[4];
#pragma unroll
    for (int nt = 0; nt < 4; ++nt) yacc[nt] = fzero;
    {
        float tt = (float)(arow + 1);
#pragma unroll
        for (int ks = 0; ks < 2; ++ks) {
            int k0 = ks * 32 + cq * 4;
            float4 v0 = xq[2 * ks];
            float4 v1 = xq[2 * ks + 1];
            {
                float e1 = __expf(lld[k0] * tt), an = lld[k0 + 1] * tt;
                float prr = e1 * __cosf(an), pri = e1 * __sinf(an);
                v0.x += prr * lpc[k0] - pri * lpc[k0 + 1];
                v0.y += prr * lpc[k0 + 1] + pri * lpc[k0];
            }
            {
                float e1 = __expf(lld[k0 + 2] * tt), an = lld[k0 + 3] * tt;
                float prr = e1 * __cosf(an), pri = e1 * __sinf(an);
                v0.z += prr * lpc[k0 + 2] - pri * lpc[k0 + 3];
                v0.w += prr * lpc[k0 + 3] + pri * lpc[k0 + 2];
            }
            {
                float e1 = __expf(lld[k0 + 16] * tt), an = lld[k0 + 17] * tt;
                float prr = e1 * __cosf(an), pri = e1 * __sinf(an);
                v1.x += prr * lpc[k0 + 16] - pri * lpc[k0 + 17];
                v1.y += prr * lpc[k0 + 17] + pri * lpc[k0 + 16];
            }
            {
                float e1 = __expf(lld[k0 + 18] * tt), an = lld[k0 + 19] * tt;
                float prr = e1 * __cosf(an), pri = e1 * __sinf(an);
                v1.z += prr * lpc[k0 + 18] - pri * lpc[k0 + 19];
                v1.w += prr * lpc[k0 + 19] + pri * lpc[k0 + 18];
            }
            bf16x8 ah, al;
            packAB(v0, v1, ah, al);
#pragma unroll
            for (int nt = 0; nt < 4; ++nt) {
                const uint4* wf = (const uint4*)&fC[((size_t)(ks * 4 + nt) * 64 + l) * 8];
                FragU BH, BL; BH.q = wf[0]; BL.q = wf[1];
                MFMA3(yacc[nt], ah, al, BH.v, BL.v);
            }
        }
    }

    // gelu(2y + hn*D) -> g split-packed into act
#pragma unroll
    for (int nt = 0; nt < 4; ++nt) {
        int ch = nt * 16 + cr;
        float sav = lsa[ch], sbv = lsb[ch], dvv = lsd[ch];
#pragma unroll
        for (int r = 0; r < 4; ++r) {
            int row = 16 * w + 4 * cq + r;
            float hv = hrow[nt * 4 + r];
            float t = 2.0f * yacc[nt][r] + (hv * sav + sbv) * dvv;
            float u2 = 1.5957691216057308f * (t + 0.044715f * t * t * t);
            float gv = t / (1.0f + __expf(-u2));
            act[row * ASTR + ch] = splitpack(gv);
        }
    }
    asm volatile("s_waitcnt lgkmcnt(0)" ::: "memory");

    // GLU 2 GEMMs (shared A-frags from act)
    const unsigned* f1 = fragL + (size_t)(lay * 4 + 2) * 4096;
    const unsigned* f2 = fragL + (size_t)(lay * 4 + 3) * 4096;
    f32x4 uacc[4], sacc[4];
#pragma unroll
    for (int nt = 0; nt < 4; ++nt) { uacc[nt] = fzero; sacc[nt] = fzero; }
#pragma unroll
    for (int ks = 0; ks < 2; ++ks) {
        int col = ks * 32 + 4 * cq;
        uint4 a0 = *(const uint4*)&act[arow * ASTR + col];
        uint4 a1 = *(const uint4*)&act[arow * ASTR + col + 16];
        union { bf16x8 v; unsigned u[4]; } H, L;
        H.u[0] = (a0.x & 0xffffu) | (a0.y << 16);
        H.u[1] = (a0.z & 0xffffu) | (a0.w << 16);
        H.u[2] = (a1.x & 0xffffu) | (a1.y << 16);
        H.u[3] = (a1.z & 0xffffu) | (a1.w << 16);
        L.u[0] = (a0.x >> 16) | (a0.y & 0xffff0000u);
        L.u[1] = (a0.z >> 16) | (a0.w & 0xffff0000u);
        L.u[2] = (a1.x >> 16) | (a1.y & 0xffff0000u);
        L.u[3] = (a1.z >> 16) | (a1.w & 0xffff0000u);
#pragma unroll
        for (int nt = 0; nt < 4; ++nt) {
            const uint4* w1f = (const uint4*)&f1[((size_t)(ks * 4 + nt) * 64 + l) * 8];
            FragU BH1, BL1; BH1.q = w1f[0]; BL1.q = w1f[1];
            MFMA3(uacc[nt], H.v, L.v, BH1.v, BL1.v);
            const uint4* w2f = (const uint4*)&f2[((size_t)(ks * 4 + nt) * 64 + l) * 8];
            FragU BH2, BL2; BH2.q = w2f[0]; BL2.q = w2f[1];
            MFMA3(sacc[nt], H.v, L.v, BH2.v, BL2.v);
        }
    }

    if (LAST) {
        float o0[4] = {0.f, 0.f, 0.f, 0.f}, o1[4] = {0.f, 0.f, 0.f, 0.f};
#pragma unroll
        for (int nt = 0; nt < 4; ++nt) {
            int ch = nt * 16 + cr;
            float bb1 = b1[lay * HD + ch], bb2 = b2[lay * HD + ch];
            float dw0 = dec_w[ch], dw1 = dec_w[64 + ch];
#pragma unroll
            for (int r = 0; r < 4; ++r) {
                float sv = sacc[nt][r] + bb2;
                float sg = 1.0f / (1.0f + __expf(-sv));
                float ho = hrow[nt * 4 + r] + (uacc[nt][r] + bb1) * sg;
                o0[r] += ho * dw0;
                o1[r] += ho * dw1;
            }
        }
#pragma unroll
        for (int r = 0; r < 4; ++r) {
#pragma unroll
            for (int m = 1; m < 16; m <<= 1) {
                o0[r] += __shfl_xor(o0[r], m, 64);
                o1[r] += __shfl_xor(o1[r], m, 64);
            }
        }
        if (cr == 0) {
            float db0 = dec_b[0], db1 = dec_b[1];
#pragma unroll
            for (int r = 0; r < 4; ++r) {
                int row = 16 * w + 4 * cq + r;
                *(float2*)&outp[(r0 + row) * 2] = make_float2(o0[r] + db0, o1[r] + db1);
            }
        }
    } else {
#pragma unroll
        for (int nt = 0; nt < 4; ++nt) {
            int ch = nt * 16 + cr;
            float bb1 = b1[lay * HD + ch], bb2 = b2[lay * HD + ch];
            float v1 = 0.0f, v2 = 0.0f;
#pragma unroll
            for (int r = 0; r < 4; ++r) {
                int row = 16 * w + 4 * cq + r;
                float sv = sacc[nt][r] + bb2;
                float sg = 1.0f / (1.0f + __expf(-sv));
                float ho = hrow[nt * 4 + r] + (uacc[nt][r] + bb1) * sg;
                hout[(r0 + row) * HD + ch] = ho;
                v1 += ho; v2 += ho * ho;
            }
            v1 += __shfl_xor(v1, 16, 64); v2 += __shfl_xor(v2, 16, 64);
            v1 += __shfl_xor(v1, 32, 64); v2 += __shfl_xor(v2, 32, 64);
            if (l < 16) { sp1[w * 64 + ch] = v1; sp2[w * 64 + ch] = v2; }
        }
        __syncthreads();
        if (tid < 64) {
            float s1 = 0.0f, s2 = 0.0f;
#pragma unroll
            for (int ww = 0; ww < 8; ++ww) { s1 += sp1[ww * 64 + tid]; s2 += sp2[ww * 64 + tid]; }
            part[tid * 1024 + blockIdx.x]        = s1;
            part[(64 + tid) * 1024 + blockIdx.x] = s2;
        }
    }
}

// ---------------------------------------------------------------- launch
extern "C" void kernel_launch(void* const* d_in, const int* in_sizes, int n_in,
                              void* d_out, int out_size, void* d_ws, size_t ws_size,
                              hipStream_t stream)
{
    (void)in_sizes; (void)n_in; (void)out_size; (void)ws_size;
    const float* x     = (const float*)d_in[0];
    const int*   gidx  = (const int*)d_in[1];
    const float* enc_w = (const float*)d_in[2];
    const float* enc_b = (const float*)d_in[3];
    const float* ctx   = (const float*)d_in[4];
    const float* Lre   = (const float*)d_in[5];
    const float* Lim   = (const float*)d_in[6];
    const float* Bre   = (const float*)d_in[7];
    const float* Bim   = (const float*)d_in[8];
    const float* Cre   = (const float*)d_in[9];
    const float* Cim   = (const float*)d_in[10];
    const float* Dv    = (const float*)d_in[11];
    const float* lstep = (const float*)d_in[12];
    const float* nsc   = (const float*)d_in[13];
    const float* nbi   = (const float*)d_in[14];
    const float* w1    = (const float*)d_in[15];
    const float* b1    = (const float*)d_in[16];
    const float* w2    = (const float*)d_in[17];
    const float* b2    = (const float*)d_in[18];
    const float* dw    = (const float*)d_in[19];
    const float* db    = (const float*)d_in[20];
    float* out = (float*)d_out;

    float* ws = (float*)d_ws;
    float* h     = ws;  ws += (size_t)T_LEN * HD;
    float* xs    = ws;  ws += (size_t)T_LEN * HD;
    float* carry = ws;  ws += (size_t)NBLK * HD;
    float* pc    = ws;  ws += (size_t)NBLK * HD;
    float* stats = ws;  ws += NLAY * 128;
    float* Lbar  = ws;  ws += NLAY * PD * 2;
    float* Ldt   = ws;  ws += NLAY * PD * 2;
    unsigned* fragE = (unsigned*)ws;  ws += 16384;
    unsigned* fragL = (unsigned*)ws;  ws += 65536;
    float* part  = ws;  ws += 128 * 1024;

    ssm_k0a<<<1, 512, 0, stream>>>(Lre, Lim, lstep, Lbar, Ldt, stats);
    ssm_k0b<<<40, 256, 0, stream>>>(Lre, Lim, lstep, Bre, Bim, Cre, Cim, w1, w2,
                                    enc_w, gidx, fragE, fragL);
    ssm_k1_encoder<<<1024, 512, 0, stream>>>(x, gidx, fragE, enc_b, ctx, h, part);
    ssm_k5_reduce<<<128, 64, 0, stream>>>(part, stats);
    for (int lay = 0; lay < NLAY; ++lay) {
        ssm_k2_bu_scan<<<NBLK, 512, 0, stream>>>(h, stats, nsc, nbi, fragL, Lbar, xs, carry, lay);
        ssm_k3_carry<<<PD, 64, 0, stream>>>(carry, Ldt, pc, lay);
        if (lay < NLAY - 1) {
            ssm_k4_out<false><<<NBLK, 512, 0, stream>>>(
                h, xs, pc, stats, nsc, nbi, Ldt, fragL, Dv, b1, b2,
                h, part, dw, db, out, lay);
            ssm_k5_reduce<<<128, 64, 0, stream>>>(part, stats + (lay + 1) * 128);
        } else {
            ssm_k4_out<true><<<NBLK, 512, 0, stream>>>(
                h, xs, pc, stats, nsc, nbi, Ldt, fragL, Dv, b1, b2,
                h, part, dw, db, out, lay);
        }
    }
}

// Round 15
// 326.291 us; speedup vs baseline: 3.6011x; 1.0594x over previous
//
#include <hip/hip_runtime.h>

#define T_LEN   131072
#define IN_DIM  256
#define HD      64
#define PD      32
#define NLAY    4
#define CHUNK   128
#define NBLK    (T_LEN / CHUNK)   // 1024
#define ASTR    68                // LDS row stride: 68 % 32 == 4 -> conflict-free column b128

typedef __attribute__((ext_vector_type(8))) short bf16x8;
typedef __attribute__((ext_vector_type(4))) float f32x4;

union FragU { uint4 q; bf16x8 v; };

// split fp32 -> two bf16 (hi in low16, lo in high16 of packed word)
__device__ __forceinline__ unsigned splitpack(float x) {
    unsigned xb = __float_as_uint(x);
    unsigned hb = (xb + 0x8000u) & 0xffff0000u;
    float lf = x - __uint_as_float(hb);
    unsigned lb = (__float_as_uint(lf) + 0x8000u) >> 16;
    return (hb >> 16) | (lb << 16);
}

// pack 8 floats (two float4 quads: k0..k0+3 and k0+16..k0+19) into hi/lo bf16x8 frags
__device__ __forceinline__ void packAB(float4 a0, float4 a1, bf16x8& hi, bf16x8& lo) {
    unsigned p0 = splitpack(a0.x), p1 = splitpack(a0.y);
    unsigned p2 = splitpack(a0.z), p3 = splitpack(a0.w);
    unsigned p4 = splitpack(a1.x), p5 = splitpack(a1.y);
    unsigned p6 = splitpack(a1.z), p7 = splitpack(a1.w);
    union { bf16x8 v; unsigned u[4]; } H, L;
    H.u[0] = (p0 & 0xffffu) | (p1 << 16);
    H.u[1] = (p2 & 0xffffu) | (p3 << 16);
    H.u[2] = (p4 & 0xffffu) | (p5 << 16);
    H.u[3] = (p6 & 0xffffu) | (p7 << 16);
    L.u[0] = (p0 >> 16) | (p1 & 0xffff0000u);
    L.u[1] = (p2 >> 16) | (p3 & 0xffff0000u);
    L.u[2] = (p4 >> 16) | (p5 & 0xffff0000u);
    L.u[3] = (p6 >> 16) | (p7 & 0xffff0000u);
    hi = H.v; lo = L.v;
}

#define MFMA3(ACC, AH, AL, BH, BL)                                              \
    ACC = __builtin_amdgcn_mfma_f32_16x16x32_bf16(AH, BH, ACC, 0, 0, 0);        \
    ACC = __builtin_amdgcn_mfma_f32_16x16x32_bf16(AH, BL, ACC, 0, 0, 0);        \
    ACC = __builtin_amdgcn_mfma_f32_16x16x32_bf16(AL, BH, ACC, 0, 0, 0);

// k mapping used consistently for A and B fragment packing
__device__ __forceinline__ int kmap(int q, int j) {
    return (j < 4) ? (q * 4 + j) : (16 + q * 4 + (j - 4));
}

// ---------------------------------------------------------------- K0a
__global__ __launch_bounds__(512) void ssm_k0a(
    const float* __restrict__ Lre, const float* __restrict__ Lim,
    const float* __restrict__ logstep,
    float* __restrict__ Lbar, float* __restrict__ Ldt, float* __restrict__ stats)
{
    int tid = threadIdx.x;
    if (tid < NLAY * PD) {
        int l = tid >> 5, p = tid & 31;
        float dt = expf(logstep[l * PD + p]);
        float lr = Lre[l * PD + p], li = Lim[l * PD + p];
        float ldr = lr * dt, ldi = li * dt;
        Ldt[tid * 2] = ldr; Ldt[tid * 2 + 1] = ldi;
        float e = expf(ldr);
        float sn, cs; sincosf(ldi, &sn, &cs);
        Lbar[tid * 2] = e * cs; Lbar[tid * 2 + 1] = e * sn;
    }
    if (tid < NLAY * 128) stats[tid] = 0.0f;
}

// ---------------------------------------------------------------- K0b: weight fragment builder
__global__ __launch_bounds__(256) void ssm_k0b(
    const float* __restrict__ Lre, const float* __restrict__ Lim,
    const float* __restrict__ logstep,
    const float* __restrict__ Bre, const float* __restrict__ Bim,
    const float* __restrict__ Cre, const float* __restrict__ Cim,
    const float* __restrict__ w1, const float* __restrict__ w2,
    const float* __restrict__ enc_w, const int* __restrict__ gptr,
    unsigned* __restrict__ fragE, unsigned* __restrict__ fragL)
{
    int fi = blockIdx.x * 256 + threadIdx.x;   // 0..10239
    if (fi >= 10240) return;
    int g = gptr[0];
    int mat, lay = 0, rem;
    unsigned* outp;
    if (fi < 2048) { mat = 0; rem = fi; outp = fragE + rem * 8; }
    else {
        int t = fi - 2048;
        lay = t / 2048;
        int r2 = t % 2048;
        mat = 1 + r2 / 512;
        rem = r2 % 512;
        outp = fragL + ((size_t)(lay * 4 + (mat - 1)) * 512 + rem) * 8;
    }
    int ks = rem / 256;
    int nt = (rem / 64) & 3;
    int lane = rem & 63;
    int q = lane >> 4;
    int n = nt * 16 + (lane & 15);

    float vals[8];
#pragma unroll
    for (int j = 0; j < 8; ++j) {
        int k = ks * 32 + kmap(q, j);
        float v;
        if (mat == 0) {
            v = (n < 56) ? enc_w[(size_t)(g * 56 + n) * IN_DIM + k] : 0.0f;
        } else if (mat == 1) {
            int p = n >> 1;
            float dt = expf(logstep[lay * PD + p]);
            float lr = Lre[lay * PD + p], li = Lim[lay * PD + p];
            float e = expf(lr * dt);
            float sn, cs; sincosf(li * dt, &sn, &cs);
            float den = lr * lr + li * li;
            float nr = e * cs - 1.0f, ni = e * sn;
            float fr = (nr * lr + ni * li) / den, fimag = (ni * lr - nr * li) / den;
            float br = Bre[(lay * PD + p) * HD + k], bi = Bim[(lay * PD + p) * HD + k];
            v = (n & 1) ? (fr * bi + fimag * br) : (fr * br - fimag * bi);
        } else if (mat == 2) {
            int p = k >> 1;
            v = (k & 1) ? -Cim[((size_t)lay * HD + n) * PD + p]
                        :  Cre[((size_t)lay * HD + n) * PD + p];
        } else if (mat == 3) {
            v = w1[((size_t)lay * HD + n) * HD + k];
        } else {
            v = w2[((size_t)lay * HD + n) * HD + k];
        }
        vals[j] = v;
    }
    unsigned p8[8];
#pragma unroll
    for (int j = 0; j < 8; ++j) p8[j] = splitpack(vals[j]);
#pragma unroll
    for (int w = 0; w < 4; ++w) {
        unsigned p0 = p8[2 * w], p1 = p8[2 * w + 1];
        outp[w]     = (p0 & 0xffffu) | (p1 << 16);
        outp[4 + w] = (p0 >> 16) | (p1 & 0xffff0000u);
    }
}

// ---------------------------------------------------------------- K5: stats partial reduce
// part layout [128][1024]; block c sums its 1024-float row (coalesced), writes statsL[c].
__global__ __launch_bounds__(64) void ssm_k5_reduce(
    const float* __restrict__ part, float* __restrict__ statsL)
{
    int c = blockIdx.x;
    int lane = threadIdx.x;
    float s = 0.0f;
#pragma unroll
    for (int j = 0; j < 4; ++j) {
        float4 v = *(const float4*)&part[c * 1024 + j * 256 + lane * 4];
        s += v.x + v.y + v.z + v.w;
    }
#pragma unroll
    for (int m = 1; m < 64; m <<= 1) s += __shfl_xor(s, m, 64);
    if (lane == 0) statsL[c] = s;
}

// ---------------------------------------------------------------- K1: encoder (MFMA, all x-quads prefetched)
__global__ __launch_bounds__(512, 4) void ssm_k1_encoder(
    const float* __restrict__ x, const int* __restrict__ gptr,
    const unsigned* __restrict__ fragE, const float* __restrict__ enc_b,
    const float* __restrict__ ctx_emb,
    float* __restrict__ h, float* __restrict__ part)
{
    __shared__ float sp1[512], sp2[512];
    int tid = threadIdx.x;
    int l = tid & 63, w = tid >> 6;
    int cq = l >> 4, cr = l & 15;
    int g = gptr[0];
    size_t r0 = (size_t)blockIdx.x * 128;
    int arow = 16 * w + cr;
    const float* xrow = &x[(r0 + arow) * IN_DIM];
    const f32x4 fzero = {0.f, 0.f, 0.f, 0.f};

    // issue all 16 x-quad loads up front (max MLP)
    float4 cur[16];
#pragma unroll
    for (int kt = 0; kt < 4; ++kt)
#pragma unroll
        for (int ks = 0; ks < 2; ++ks) {
            cur[kt * 4 + 2 * ks]     = *(const float4*)&xrow[kt * 64 + ks * 32 + cq * 4];
            cur[kt * 4 + 2 * ks + 1] = *(const float4*)&xrow[kt * 64 + ks * 32 + cq * 4 + 16];
        }

    f32x4 acc[4];
#pragma unroll
    for (int nt = 0; nt < 4; ++nt) acc[nt] = fzero;

#pragma unroll
    for (int kt = 0; kt < 4; ++kt)
#pragma unroll
        for (int ks = 0; ks < 2; ++ks) {
            bf16x8 ah, al;
            packAB(cur[kt * 4 + 2 * ks], cur[kt * 4 + 2 * ks + 1], ah, al);
            int ksg = kt * 2 + ks;
#pragma unroll
            for (int nt = 0; nt < 4; ++nt) {
                const uint4* wf = (const uint4*)&fragE[((size_t)(ksg * 4 + nt) * 64 + l) * 8];
                FragU BH, BL; BH.q = wf[0]; BL.q = wf[1];
                MFMA3(acc[nt], ah, al, BH.v, BL.v);
            }
        }
    // epilogue: bias/ctx, store h, stats partials
#pragma unroll
    for (int nt = 0; nt < 4; ++nt) {
        int ch = nt * 16 + cr;
        float eb = (ch < 56) ? enc_b[g * 56 + ch] : 0.0f;
        bool isctx = (ch >= 56);
        float cv = isctx ? ctx_emb[g * 8 + (ch - 56)] : 0.0f;
        float v1 = 0.0f, v2 = 0.0f;
#pragma unroll
        for (int r = 0; r < 4; ++r) {
            float val = isctx ? cv : (acc[nt][r] + eb);
            h[(r0 + 16 * w + 4 * cq + r) * HD + ch] = val;
            v1 += val; v2 += val * val;
        }
        v1 += __shfl_xor(v1, 16, 64); v2 += __shfl_xor(v2, 16, 64);
        v1 += __shfl_xor(v1, 32, 64); v2 += __shfl_xor(v2, 32, 64);
        if (l < 16) { sp1[w * 64 + ch] = v1; sp2[w * 64 + ch] = v2; }
    }
    __syncthreads();
    if (tid < 64) {
        float s1 = 0.0f, s2 = 0.0f;
#pragma unroll
        for (int ww = 0; ww < 8; ++ww) { s1 += sp1[ww * 64 + tid]; s2 += sp2[ww * 64 + tid]; }
        part[tid * 1024 + blockIdx.x]        = s1;   // no atomics: block owns its column
        part[(64 + tid) * 1024 + blockIdx.x] = s2;
    }
}

// ---------------------------------------------------------------- K2: hn -> Bu (MFMA direct) -> local scan
__global__ __launch_bounds__(512, 4) void ssm_k2_bu_scan(
    const float* __restrict__ h, const float* __restrict__ stats,
    const float* __restrict__ nscale, const float* __restrict__ nbias,
    const unsigned* __restrict__ fragL, const float* __restrict__ Lbar,
    float* __restrict__ xs, float* __restrict__ carry, int lay)
{
    __shared__ __attribute__((aligned(16))) float bf[128 * ASTR];
    __shared__ float lsa[HD], lsb[HD];
    int tid = threadIdx.x;
    int l = tid & 63, w = tid >> 6;
    int cq = l >> 4, cr = l & 15;
    size_t r0 = (size_t)blockIdx.x * CHUNK;
    int arow = 16 * w + cr;
    const f32x4 fzero = {0.f, 0.f, 0.f, 0.f};

    if (tid < HD) {
        float s1 = stats[lay * 128 + tid], s2 = stats[lay * 128 + 64 + tid];
        float mu = s1 * (1.0f / T_LEN);
        float var = fmaxf(s2 * (1.0f / T_LEN) - mu * mu, 0.0f);
        float sc = nscale[lay * HD + tid] * rsqrtf(var + 1e-5f);
        lsa[tid] = sc;
        lsb[tid] = nbias[lay * HD + tid] - mu * sc;
    }
    __syncthreads();

    const float* hrowp = &h[(r0 + arow) * HD];
    const unsigned* fB = fragL + (size_t)(lay * 4 + 0) * 4096;
    f32x4 acc[4];
#pragma unroll
    for (int nt = 0; nt < 4; ++nt) acc[nt] = fzero;
#pragma unroll
    for (int ks = 0; ks < 2; ++ks) {
        int k0 = ks * 32 + cq * 4;
        float4 c0 = *(const float4*)&hrowp[k0];
        float4 c1 = *(const float4*)&hrowp[k0 + 16];
        c0.x = c0.x * lsa[k0]      + lsb[k0];
        c0.y = c0.y * lsa[k0 + 1]  + lsb[k0 + 1];
        c0.z = c0.z * lsa[k0 + 2]  + lsb[k0 + 2];
        c0.w = c0.w * lsa[k0 + 3]  + lsb[k0 + 3];
        c1.x = c1.x * lsa[k0 + 16] + lsb[k0 + 16];
        c1.y = c1.y * lsa[k0 + 17] + lsb[k0 + 17];
        c1.z = c1.z * lsa[k0 + 18] + lsb[k0 + 18];
        c1.w = c1.w * lsa[k0 + 19] + lsb[k0 + 19];
        bf16x8 ah, al;
        packAB(c0, c1, ah, al);
#pragma unroll
        for (int nt = 0; nt < 4; ++nt) {
            const uint4* wf = (const uint4*)&fB[((size_t)(ks * 4 + nt) * 64 + l) * 8];
            FragU BH, BL; BH.q = wf[0]; BL.q = wf[1];
            MFMA3(acc[nt], ah, al, BH.v, BL.v);
        }
    }
#pragma unroll
    for (int nt = 0; nt < 4; ++nt)
#pragma unroll
        for (int r = 0; r < 4; ++r)
            bf[(16 * w + 4 * cq + r) * ASTR + nt * 16 + cr] = acc[nt][r];
    __syncthreads();

    if (tid < 64) {
        int p = l >> 1;
        float Lr = Lbar[(lay * PD + p) * 2];
        float Lj = Lbar[(lay * PD + p) * 2 + 1];
        float csn = (l & 1) ? Lj : -Lj;
        float xv = 0.0f;
        for (int t = 0; t < CHUNK; ++t) {
            float b = bf[t * ASTR + l];
            float xo = __shfl_xor(xv, 1, 64);
            xv = Lr * xv + csn * xo + b;
            bf[t * ASTR + l] = xv;
        }
        carry[(size_t)blockIdx.x * 64 + l] = xv;
    }
    __syncthreads();
#pragma unroll
    for (int j = 0; j < 4; ++j) {
        float4 v = *(float4*)&bf[arow * ASTR + cq * 16 + j * 4];
        *(float4*)&xs[(r0 + arow) * HD + cq * 16 + j * 4] = v;
    }
}

// ---------------------------------------------------------------- K3: cross-chunk carry scan
__global__ __launch_bounds__(64) void ssm_k3_carry(
    const float* __restrict__ carry, const float* __restrict__ Ldt,
    float* __restrict__ pc, int lay)
{
    int p = blockIdx.x;
    int lane = threadIdx.x;
    float ldr = Ldt[(lay * PD + p) * 2], ldi = Ldt[(lay * PD + p) * 2 + 1];
    float er = __expf(ldr * (float)CHUNK);
    float an = ldi * (float)CHUNK;
    float lcr = er * __cosf(an), lci = er * __sinf(an);
    float cr[16], ci[16];
#pragma unroll
    for (int j = 0; j < 16; ++j) {
        cr[j] = carry[(size_t)(lane * 16 + j) * 64 + 2 * p];
        ci[j] = carry[(size_t)(lane * 16 + j) * 64 + 2 * p + 1];
    }
    float ur = 0.0f, ui = 0.0f;
#pragma unroll
    for (int j = 0; j < 16; ++j) {
        float nr = lcr * ur - lci * ui + cr[j];
        float ni = lcr * ui + lci * ur + ci[j];
        ur = nr; ui = ni;
    }
    float mr = lcr, mi = lci;
#pragma unroll
    for (int s = 0; s < 4; ++s) { float t = mr * mr - mi * mi; mi = 2.0f * mr * mi; mr = t; }
#pragma unroll
    for (int d = 1; d < 64; d <<= 1) {
        float tr = __shfl_up(ur, d, 64);
        float ti = __shfl_up(ui, d, 64);
        if (lane >= d) { ur = mr * tr - mi * ti + ur; ui = mr * ti + mi * tr + ui; }
        float t = mr * mr - mi * mi; mi = 2.0f * mr * mi; mr = t;
    }
    float pr = __shfl_up(ur, 1, 64), pi = __shfl_up(ui, 1, 64);
    float xr = (lane == 0) ? 0.0f : pr;
    float xi = (lane == 0) ? 0.0f : pi;
#pragma unroll
    for (int j = 0; j < 16; ++j) {
        pc[(size_t)(lane * 16 + j) * 64 + 2 * p]     = xr;
        pc[(size_t)(lane * 16 + j) * 64 + 2 * p + 1] = xi;
        float nr = lcr * xr - lci * xi + cr[j];
        float ni = lcr * xi + lci * xr + ci[j];
        xr = nr; xi = ni;
    }
}

// ---------------------------------------------------------------- K4: fixup + C-proj + gelu + GLU + residual (MFMA)
template <bool LAST>
__global__ __launch_bounds__(512, 4) void ssm_k4_out(
    const float* __restrict__ h, const float* __restrict__ xs,
    const float* __restrict__ pc, const float* __restrict__ stats,
    const float* __restrict__ nscale, const float* __restrict__ nbias,
    const float* __restrict__ Ldt, const unsigned* __restrict__ fragL,
    const float* __restrict__ Dv,
    const float* __restrict__ b1, const float* __restrict__ b2,
    float* __restrict__ hout, float* __restrict__ part,
    const float* __restrict__ dec_w, const float* __restrict__ dec_b,
    float* __restrict__ outp, int lay)
{
    __shared__ __attribute__((aligned(16))) unsigned act[128 * ASTR];
    __shared__ float lsa[HD], lsb[HD], lsd[HD], lpc[HD], lld[HD];
    __shared__ float sp1[512], sp2[512];
    int tid = threadIdx.x;
    int l = tid & 63, w = tid >> 6;
    int cq = l >> 4, cr = l & 15;
    size_t r0 = (size_t)blockIdx.x * CHUNK;
    int arow = 16 * w + cr;
    const f32x4 fzero = {0.f, 0.f, 0.f, 0.f};

    if (tid < HD) {
        float s1 = stats[lay * 128 + tid], s2 = stats[lay * 128 + 64 + tid];
        float mu = s1 * (1.0f / T_LEN);
        float var = fmaxf(s2 * (1.0f / T_LEN) - mu * mu, 0.0f);
        float sc = nscale[lay * HD + tid] * rsqrtf(var + 1e-5f);
        lsa[tid] = sc;
        lsb[tid] = nbias[lay * HD + tid] - mu * sc;
        lsd[tid] = Dv[lay * HD + tid];
        lpc[tid] = pc[(size_t)blockIdx.x * 64 + tid];
        lld[tid] = Ldt[lay * 64 + tid];
    }
    __syncthreads();

    // phase 1+2: xs direct A-frag load + carry fixup (in regs) -> C-proj GEMM
    const unsigned* fC = fragL + (size_t)(lay * 4 + 1) * 4096;
    f32x4 yacc[4];
#pragma unroll
    for (int nt = 0; nt < 4; ++nt) yacc[nt] = fzero;
    {
        const float* xrowp = &xs[(r0 + arow) * HD];
        float tt = (float)(arow + 1);
#pragma unroll
        for (int ks = 0; ks < 2; ++ks) {
            int k0 = ks * 32 + cq * 4;
            float4 v0 = *(const float4*)&xrowp[k0];
            float4 v1 = *(const float4*)&xrowp[k0 + 16];
            {
                float e1 = __expf(lld[k0] * tt), an = lld[k0 + 1] * tt;
                float prr = e1 * __cosf(an), pri = e1 * __sinf(an);
                v0.x += prr * lpc[k0] - pri * lpc[k0 + 1];
                v0.y += prr * lpc[k0 + 1] + pri * lpc[k0];
            }
            {
                float e1 = __expf(lld[k0 + 2] * tt), an = lld[k0 + 3] * tt;
                float prr = e1 * __cosf(an), pri = e1 * __sinf(an);
                v0.z += prr * lpc[k0 + 2] - pri * lpc[k0 + 3];
                v0.w += prr * lpc[k0 + 3] + pri * lpc[k0 + 2];
            }
            {
                float e1 = __expf(lld[k0 + 16] * tt), an = lld[k0 + 17] * tt;
                float prr = e1 * __cosf(an), pri = e1 * __sinf(an);
                v1.x += prr * lpc[k0 + 16] - pri * lpc[k0 + 17];
                v1.y += prr * lpc[k0 + 17] + pri * lpc[k0 + 16];
            }
            {
                float e1 = __expf(lld[k0 + 18] * tt), an = lld[k0 + 19] * tt;
                float prr = e1 * __cosf(an), pri = e1 * __sinf(an);
                v1.z += prr * lpc[k0 + 18] - pri * lpc[k0 + 19];
                v1.w += prr * lpc[k0 + 19] + pri * lpc[k0 + 18];
            }
            bf16x8 ah, al;
            packAB(v0, v1, ah, al);
#pragma unroll
            for (int nt = 0; nt < 4; ++nt) {
                const uint4* wf = (const uint4*)&fC[((size_t)(ks * 4 + nt) * 64 + l) * 8];
                FragU BH, BL; BH.q = wf[0]; BL.q = wf[1];
                MFMA3(yacc[nt], ah, al, BH.v, BL.v);
            }
        }
    }

    // phase 3: h load (C/D positions), gelu(2y + hn*D) -> g split-packed into act
    float hrow[16];
#pragma unroll
    for (int nt = 0; nt < 4; ++nt) {
        int ch = nt * 16 + cr;
        float sav = lsa[ch], sbv = lsb[ch], dvv = lsd[ch];
#pragma unroll
        for (int r = 0; r < 4; ++r) {
            int row = 16 * w + 4 * cq + r;
            float hv = h[(r0 + row) * HD + ch];
            hrow[nt * 4 + r] = hv;
            float t = 2.0f * yacc[nt][r] + (hv * sav + sbv) * dvv;
            float u2 = 1.5957691216057308f * (t + 0.044715f * t * t * t);
            float gv = t / (1.0f + __expf(-u2));
            act[row * ASTR + ch] = splitpack(gv);
        }
    }
    asm volatile("s_waitcnt lgkmcnt(0)" ::: "memory");

    // phase 4: GLU 2 GEMMs (shared A-frags from act)
    const unsigned* f1 = fragL + (size_t)(lay * 4 + 2) * 4096;
    const unsigned* f2 = fragL + (size_t)(lay * 4 + 3) * 4096;
    f32x4 uacc[4], sacc[4];
#pragma unroll
    for (int nt = 0; nt < 4; ++nt) { uacc[nt] = fzero; sacc[nt] = fzero; }
#pragma unroll
    for (int ks = 0; ks < 2; ++ks) {
        int col = ks * 32 + 4 * cq;
        uint4 a0 = *(const uint4*)&act[arow * ASTR + col];
        uint4 a1 = *(const uint4*)&act[arow * ASTR + col + 16];
        union { bf16x8 v; unsigned u[4]; } H, L;
        H.u[0] = (a0.x & 0xffffu) | (a0.y << 16);
        H.u[1] = (a0.z & 0xffffu) | (a0.w << 16);
        H.u[2] = (a1.x & 0xffffu) | (a1.y << 16);
        H.u[3] = (a1.z & 0xffffu) | (a1.w << 16);
        L.u[0] = (a0.x >> 16) | (a0.y & 0xffff0000u);
        L.u[1] = (a0.z >> 16) | (a0.w & 0xffff0000u);
        L.u[2] = (a1.x >> 16) | (a1.y & 0xffff0000u);
        L.u[3] = (a1.z >> 16) | (a1.w & 0xffff0000u);
#pragma unroll
        for (int nt = 0; nt < 4; ++nt) {
            const uint4* w1f = (const uint4*)&f1[((size_t)(ks * 4 + nt) * 64 + l) * 8];
            FragU BH1, BL1; BH1.q = w1f[0]; BL1.q = w1f[1];
            MFMA3(uacc[nt], H.v, L.v, BH1.v, BL1.v);
            const uint4* w2f = (const uint4*)&f2[((size_t)(ks * 4 + nt) * 64 + l) * 8];
            FragU BH2, BL2; BH2.q = w2f[0]; BL2.q = w2f[1];
            MFMA3(sacc[nt], H.v, L.v, BH2.v, BL2.v);
        }
    }

    // phase 5: epilogue
    if (LAST) {
        float o0[4] = {0.f, 0.f, 0.f, 0.f}, o1[4] = {0.f, 0.f, 0.f, 0.f};
#pragma unroll
        for (int nt = 0; nt < 4; ++nt) {
            int ch = nt * 16 + cr;
            float bb1 = b1[lay * HD + ch], bb2 = b2[lay * HD + ch];
            float dw0 = dec_w[ch], dw1 = dec_w[64 + ch];
#pragma unroll
            for (int r = 0; r < 4; ++r) {
                float sv = sacc[nt][r] + bb2;
                float sg = 1.0f / (1.0f + __expf(-sv));
                float ho = hrow[nt * 4 + r] + (uacc[nt][r] + bb1) * sg;
                o0[r] += ho * dw0;
                o1[r] += ho * dw1;
            }
        }
#pragma unroll
        for (int r = 0; r < 4; ++r) {
#pragma unroll
            for (int m = 1; m < 16; m <<= 1) {
                o0[r] += __shfl_xor(o0[r], m, 64);
                o1[r] += __shfl_xor(o1[r], m, 64);
            }
        }
        if (cr == 0) {
            float db0 = dec_b[0], db1 = dec_b[1];
#pragma unroll
            for (int r = 0; r < 4; ++r) {
                int row = 16 * w + 4 * cq + r;
                *(float2*)&outp[(r0 + row) * 2] = make_float2(o0[r] + db0, o1[r] + db1);
            }
        }
    } else {
#pragma unroll
        for (int nt = 0; nt < 4; ++nt) {
            int ch = nt * 16 + cr;
            float bb1 = b1[lay * HD + ch], bb2 = b2[lay * HD + ch];
            float v1 = 0.0f, v2 = 0.0f;
#pragma unroll
            for (int r = 0; r < 4; ++r) {
                int row = 16 * w + 4 * cq + r;
                float sv = sacc[nt][r] + bb2;
                float sg = 1.0f / (1.0f + __expf(-sv));
                float ho = hrow[nt * 4 + r] + (uacc[nt][r] + bb1) * sg;
                hout[(r0 + row) * HD + ch] = ho;
                v1 += ho; v2 += ho * ho;
            }
            v1 += __shfl_xor(v1, 16, 64); v2 += __shfl_xor(v2, 16, 64);
            v1 += __shfl_xor(v1, 32, 64); v2 += __shfl_xor(v2, 32, 64);
            if (l < 16) { sp1[w * 64 + ch] = v1; sp2[w * 64 + ch] = v2; }
        }
        __syncthreads();
        if (tid < 64) {
            float s1 = 0.0f, s2 = 0.0f;
#pragma unroll
            for (int ww = 0; ww < 8; ++ww) { s1 += sp1[ww * 64 + tid]; s2 += sp2[ww * 64 + tid]; }
            part[tid * 1024 + blockIdx.x]        = s1;   // no atomics
            part[(64 + tid) * 1024 + blockIdx.x] = s2;
        }
    }
}

// ---------------------------------------------------------------- launch
extern "C" void kernel_launch(void* const* d_in, const int* in_sizes, int n_in,
                              void* d_out, int out_size, void* d_ws, size_t ws_size,
                              hipStream_t stream)
{
    (void)in_sizes; (void)n_in; (void)out_size; (void)ws_size;
    const float* x     = (const float*)d_in[0];
    const int*   gidx  = (const int*)d_in[1];
    const float* enc_w = (const float*)d_in[2];
    const float* enc_b = (const float*)d_in[3];
    const float* ctx   = (const float*)d_in[4];
    const float* Lre   = (const float*)d_in[5];
    const float* Lim   = (const float*)d_in[6];
    const float* Bre   = (const float*)d_in[7];
    const float* Bim   = (const float*)d_in[8];
    const float* Cre   = (const float*)d_in[9];
    const float* Cim   = (const float*)d_in[10];
    const float* Dv    = (const float*)d_in[11];
    const float* lstep = (const float*)d_in[12];
    const float* nsc   = (const float*)d_in[13];
    const float* nbi   = (const float*)d_in[14];
    const float* w1    = (const float*)d_in[15];
    const float* b1    = (const float*)d_in[16];
    const float* w2    = (const float*)d_in[17];
    const float* b2    = (const float*)d_in[18];
    const float* dw    = (const float*)d_in[19];
    const float* db    = (const float*)d_in[20];
    float* out = (float*)d_out;

    float* ws = (float*)d_ws;
    float* h     = ws;  ws += (size_t)T_LEN * HD;
    float* xs    = ws;  ws += (size_t)T_LEN * HD;
    float* carry = ws;  ws += (size_t)NBLK * HD;
    float* pc    = ws;  ws += (size_t)NBLK * HD;
    float* stats = ws;  ws += NLAY * 128;
    float* Lbar  = ws;  ws += NLAY * PD * 2;
    float* Ldt   = ws;  ws += NLAY * PD * 2;
    unsigned* fragE = (unsigned*)ws;  ws += 16384;
    unsigned* fragL = (unsigned*)ws;  ws += 65536;
    float* part  = ws;  ws += 128 * 1024;

    ssm_k0a<<<1, 512, 0, stream>>>(Lre, Lim, lstep, Lbar, Ldt, stats);
    ssm_k0b<<<40, 256, 0, stream>>>(Lre, Lim, lstep, Bre, Bim, Cre, Cim, w1, w2,
                                    enc_w, gidx, fragE, fragL);
    ssm_k1_encoder<<<1024, 512, 0, stream>>>(x, gidx, fragE, enc_b, ctx, h, part);
    ssm_k5_reduce<<<128, 64, 0, stream>>>(part, stats);
    for (int lay = 0; lay < NLAY; ++lay) {
        ssm_k2_bu_scan<<<NBLK, 512, 0, stream>>>(h, stats, nsc, nbi, fragL, Lbar, xs, carry, lay);
        ssm_k3_carry<<<PD, 64, 0, stream>>>(carry, Ldt, pc, lay);
        if (lay < NLAY - 1) {
            ssm_k4_out<false><<<NBLK, 512, 0, stream>>>(
                h, xs, pc, stats, nsc, nbi, Ldt, fragL, Dv, b1, b2,
                h, part, dw, db, out, lay);
            ssm_k5_reduce<<<128, 64, 0, stream>>>(part, stats + (lay + 1) * 128);
        } else {
            ssm_k4_out<true><<<NBLK, 512, 0, stream>>>(
                h, xs, pc, stats, nsc, nbi, Ldt, fragL, Dv, b1, b2,
                h, part, dw, db, out, lay);
        }
    }
}

// Round 16
// 271.580 us; speedup vs baseline: 4.3265x; 1.2015x over previous
//
#include <hip/hip_runtime.h>

#define T_LEN   131072
#define IN_DIM  256
#define HD      64
#define PD      32
#define NLAY    4
#define CHUNK   128
#define NBLK    (T_LEN / CHUNK)   // 1024
#define ASTR    68                // LDS row stride: 68 % 32 == 4 -> conflict-free column b128

typedef __attribute__((ext_vector_type(8))) short bf16x8;
typedef __attribute__((ext_vector_type(4))) float f32x4;

union FragU { uint4 q; bf16x8 v; };

// split fp32 -> two bf16 (hi in low16, lo in high16 of packed word)
__device__ __forceinline__ unsigned splitpack(float x) {
    unsigned xb = __float_as_uint(x);
    unsigned hb = (xb + 0x8000u) & 0xffff0000u;
    float lf = x - __uint_as_float(hb);
    unsigned lb = (__float_as_uint(lf) + 0x8000u) >> 16;
    return (hb >> 16) | (lb << 16);
}

__device__ __forceinline__ void packAB(float4 a0, float4 a1, bf16x8& hi, bf16x8& lo) {
    unsigned p0 = splitpack(a0.x), p1 = splitpack(a0.y);
    unsigned p2 = splitpack(a0.z), p3 = splitpack(a0.w);
    unsigned p4 = splitpack(a1.x), p5 = splitpack(a1.y);
    unsigned p6 = splitpack(a1.z), p7 = splitpack(a1.w);
    union { bf16x8 v; unsigned u[4]; } H, L;
    H.u[0] = (p0 & 0xffffu) | (p1 << 16);
    H.u[1] = (p2 & 0xffffu) | (p3 << 16);
    H.u[2] = (p4 & 0xffffu) | (p5 << 16);
    H.u[3] = (p6 & 0xffffu) | (p7 << 16);
    L.u[0] = (p0 >> 16) | (p1 & 0xffff0000u);
    L.u[1] = (p2 >> 16) | (p3 & 0xffff0000u);
    L.u[2] = (p4 >> 16) | (p5 & 0xffff0000u);
    L.u[3] = (p6 >> 16) | (p7 & 0xffff0000u);
    hi = H.v; lo = L.v;
}

#define MFMA3(ACC, AH, AL, BH, BL)                                              \
    ACC = __builtin_amdgcn_mfma_f32_16x16x32_bf16(AH, BH, ACC, 0, 0, 0);        \
    ACC = __builtin_amdgcn_mfma_f32_16x16x32_bf16(AH, BL, ACC, 0, 0, 0);        \
    ACC = __builtin_amdgcn_mfma_f32_16x16x32_bf16(AL, BH, ACC, 0, 0, 0);

__device__ __forceinline__ int kmap(int q, int j) {
    return (j < 4) ? (q * 4 + j) : (16 + q * 4 + (j - 4));
}

// ---------------------------------------------------------------- K0a
__global__ __launch_bounds__(512) void ssm_k0a(
    const float* __restrict__ Lre, const float* __restrict__ Lim,
    const float* __restrict__ logstep,
    float* __restrict__ Lbar, float* __restrict__ Ldt, float* __restrict__ stats)
{
    int tid = threadIdx.x;
    if (tid < NLAY * PD) {
        int l = tid >> 5, p = tid & 31;
        float dt = expf(logstep[l * PD + p]);
        float lr = Lre[l * PD + p], li = Lim[l * PD + p];
        float ldr = lr * dt, ldi = li * dt;
        Ldt[tid * 2] = ldr; Ldt[tid * 2 + 1] = ldi;
        float e = expf(ldr);
        float sn, cs; sincosf(ldi, &sn, &cs);
        Lbar[tid * 2] = e * cs; Lbar[tid * 2 + 1] = e * sn;
    }
    if (tid < NLAY * 128) stats[tid] = 0.0f;
}

// ---------------------------------------------------------------- K0b: weight fragment builder
__global__ __launch_bounds__(256) void ssm_k0b(
    const float* __restrict__ Lre, const float* __restrict__ Lim,
    const float* __restrict__ logstep,
    const float* __restrict__ Bre, const float* __restrict__ Bim,
    const float* __restrict__ Cre, const float* __restrict__ Cim,
    const float* __restrict__ w1, const float* __restrict__ w2,
    const float* __restrict__ enc_w, const int* __restrict__ gptr,
    unsigned* __restrict__ fragE, unsigned* __restrict__ fragL)
{
    int fi = blockIdx.x * 256 + threadIdx.x;
    if (fi >= 10240) return;
    int g = gptr[0];
    int mat, lay = 0, rem;
    unsigned* outp;
    if (fi < 2048) { mat = 0; rem = fi; outp = fragE + rem * 8; }
    else {
        int t = fi - 2048;
        lay = t / 2048;
        int r2 = t % 2048;
        mat = 1 + r2 / 512;
        rem = r2 % 512;
        outp = fragL + ((size_t)(lay * 4 + (mat - 1)) * 512 + rem) * 8;
    }
    int ks = rem / 256;
    int nt = (rem / 64) & 3;
    int lane = rem & 63;
    int q = lane >> 4;
    int n = nt * 16 + (lane & 15);

    float vals[8];
#pragma unroll
    for (int j = 0; j < 8; ++j) {
        int k = ks * 32 + kmap(q, j);
        float v;
        if (mat == 0) {
            v = (n < 56) ? enc_w[(size_t)(g * 56 + n) * IN_DIM + k] : 0.0f;
        } else if (mat == 1) {
            int p = n >> 1;
            float dt = expf(logstep[lay * PD + p]);
            float lr = Lre[lay * PD + p], li = Lim[lay * PD + p];
            float e = expf(lr * dt);
            float sn, cs; sincosf(li * dt, &sn, &cs);
            float den = lr * lr + li * li;
            float nr = e * cs - 1.0f, ni = e * sn;
            float fr = (nr * lr + ni * li) / den, fimag = (ni * lr - nr * li) / den;
            float br = Bre[(lay * PD + p) * HD + k], bi = Bim[(lay * PD + p) * HD + k];
            v = (n & 1) ? (fr * bi + fimag * br) : (fr * br - fimag * bi);
        } else if (mat == 2) {
            int p = k >> 1;
            v = (k & 1) ? -Cim[((size_t)lay * HD + n) * PD + p]
                        :  Cre[((size_t)lay * HD + n) * PD + p];
        } else if (mat == 3) {
            v = w1[((size_t)lay * HD + n) * HD + k];
        } else {
            v = w2[((size_t)lay * HD + n) * HD + k];
        }
        vals[j] = v;
    }
    unsigned p8[8];
#pragma unroll
    for (int j = 0; j < 8; ++j) p8[j] = splitpack(vals[j]);
#pragma unroll
    for (int w = 0; w < 4; ++w) {
        unsigned p0 = p8[2 * w], p1 = p8[2 * w + 1];
        outp[w]     = (p0 & 0xffffu) | (p1 << 16);
        outp[4 + w] = (p0 >> 16) | (p1 & 0xffff0000u);
    }
}

// ---------------------------------------------------------------- K5: stats partial reduce
__global__ __launch_bounds__(64) void ssm_k5_reduce(
    const float* __restrict__ part, float* __restrict__ statsL)
{
    int c = blockIdx.x;
    int lane = threadIdx.x;
    float s = 0.0f;
#pragma unroll
    for (int j = 0; j < 4; ++j) {
        float4 v = *(const float4*)&part[c * 1024 + j * 256 + lane * 4];
        s += v.x + v.y + v.z + v.w;
    }
#pragma unroll
    for (int m = 1; m < 64; m <<= 1) s += __shfl_xor(s, m, 64);
    if (lane == 0) statsL[c] = s;
}

// ---------------------------------------------------------------- K1: encoder (MFMA, all x-quads prefetched)
__global__ __launch_bounds__(512, 4) void ssm_k1_encoder(
    const float* __restrict__ x, const int* __restrict__ gptr,
    const unsigned* __restrict__ fragE, const float* __restrict__ enc_b,
    const float* __restrict__ ctx_emb,
    float* __restrict__ h, float* __restrict__ part)
{
    __shared__ float sp1[512], sp2[512];
    int tid = threadIdx.x;
    int l = tid & 63, w = tid >> 6;
    int cq = l >> 4, cr = l & 15;
    int g = gptr[0];
    size_t r0 = (size_t)blockIdx.x * 128;
    int arow = 16 * w + cr;
    const float* xrow = &x[(r0 + arow) * IN_DIM];
    const f32x4 fzero = {0.f, 0.f, 0.f, 0.f};

    float4 cur[16];
#pragma unroll
    for (int kt = 0; kt < 4; ++kt)
#pragma unroll
        for (int ks = 0; ks < 2; ++ks) {
            cur[kt * 4 + 2 * ks]     = *(const float4*)&xrow[kt * 64 + ks * 32 + cq * 4];
            cur[kt * 4 + 2 * ks + 1] = *(const float4*)&xrow[kt * 64 + ks * 32 + cq * 4 + 16];
        }

    f32x4 acc[4];
#pragma unroll
    for (int nt = 0; nt < 4; ++nt) acc[nt] = fzero;

#pragma unroll
    for (int kt = 0; kt < 4; ++kt)
#pragma unroll
        for (int ks = 0; ks < 2; ++ks) {
            bf16x8 ah, al;
            packAB(cur[kt * 4 + 2 * ks], cur[kt * 4 + 2 * ks + 1], ah, al);
            int ksg = kt * 2 + ks;
#pragma unroll
            for (int nt = 0; nt < 4; ++nt) {
                const uint4* wf = (const uint4*)&fragE[((size_t)(ksg * 4 + nt) * 64 + l) * 8];
                FragU BH, BL; BH.q = wf[0]; BL.q = wf[1];
                MFMA3(acc[nt], ah, al, BH.v, BL.v);
            }
        }
#pragma unroll
    for (int nt = 0; nt < 4; ++nt) {
        int ch = nt * 16 + cr;
        float eb = (ch < 56) ? enc_b[g * 56 + ch] : 0.0f;
        bool isctx = (ch >= 56);
        float cv = isctx ? ctx_emb[g * 8 + (ch - 56)] : 0.0f;
        float v1 = 0.0f, v2 = 0.0f;
#pragma unroll
        for (int r = 0; r < 4; ++r) {
            float val = isctx ? cv : (acc[nt][r] + eb);
            h[(r0 + 16 * w + 4 * cq + r) * HD + ch] = val;
            v1 += val; v2 += val * val;
        }
        v1 += __shfl_xor(v1, 16, 64); v2 += __shfl_xor(v2, 16, 64);
        v1 += __shfl_xor(v1, 32, 64); v2 += __shfl_xor(v2, 32, 64);
        if (l < 16) { sp1[w * 64 + ch] = v1; sp2[w * 64 + ch] = v2; }
    }
    __syncthreads();
    if (tid < 64) {
        float s1 = 0.0f, s2 = 0.0f;
#pragma unroll
        for (int ww = 0; ww < 8; ++ww) { s1 += sp1[ww * 64 + tid]; s2 += sp2[ww * 64 + tid]; }
        part[tid * 1024 + blockIdx.x]        = s1;
        part[(64 + tid) * 1024 + blockIdx.x] = s2;
    }
}

// ---------------------------------------------------------------- K2: hn -> Bu (MFMA) -> 3-phase parallel scan -> xs (bf16)
__global__ __launch_bounds__(512, 4) void ssm_k2_bu_scan(
    const float* __restrict__ h, const float* __restrict__ stats,
    const float* __restrict__ nscale, const float* __restrict__ nbias,
    const unsigned* __restrict__ fragL, const float* __restrict__ Lbar,
    const float* __restrict__ Ldt,
    unsigned short* __restrict__ xs, float* __restrict__ carry, int lay)
{
    __shared__ __attribute__((aligned(16))) float bf[128 * ASTR];   // 34816 B
    __shared__ float lsa[HD], lsb[HD], lld[HD];
    __shared__ float agg[8 * 64], pref[8 * 64];                     // 4096 B
    int tid = threadIdx.x;
    int l = tid & 63, w = tid >> 6;
    int cq = l >> 4, cr = l & 15;
    size_t r0 = (size_t)blockIdx.x * CHUNK;
    int arow = 16 * w + cr;
    const f32x4 fzero = {0.f, 0.f, 0.f, 0.f};

    if (tid < HD) {
        float s1 = stats[lay * 128 + tid], s2 = stats[lay * 128 + 64 + tid];
        float mu = s1 * (1.0f / T_LEN);
        float var = fmaxf(s2 * (1.0f / T_LEN) - mu * mu, 0.0f);
        float sc = nscale[lay * HD + tid] * rsqrtf(var + 1e-5f);
        lsa[tid] = sc;
        lsb[tid] = nbias[lay * HD + tid] - mu * sc;
        lld[tid] = Ldt[lay * 64 + tid];
    }
    __syncthreads();

    const float* hrowp = &h[(r0 + arow) * HD];
    const unsigned* fB = fragL + (size_t)(lay * 4 + 0) * 4096;
    f32x4 acc[4];
#pragma unroll
    for (int nt = 0; nt < 4; ++nt) acc[nt] = fzero;
#pragma unroll
    for (int ks = 0; ks < 2; ++ks) {
        int k0 = ks * 32 + cq * 4;
        float4 c0 = *(const float4*)&hrowp[k0];
        float4 c1 = *(const float4*)&hrowp[k0 + 16];
        c0.x = c0.x * lsa[k0]      + lsb[k0];
        c0.y = c0.y * lsa[k0 + 1]  + lsb[k0 + 1];
        c0.z = c0.z * lsa[k0 + 2]  + lsb[k0 + 2];
        c0.w = c0.w * lsa[k0 + 3]  + lsb[k0 + 3];
        c1.x = c1.x * lsa[k0 + 16] + lsb[k0 + 16];
        c1.y = c1.y * lsa[k0 + 17] + lsb[k0 + 17];
        c1.z = c1.z * lsa[k0 + 18] + lsb[k0 + 18];
        c1.w = c1.w * lsa[k0 + 19] + lsb[k0 + 19];
        bf16x8 ah, al;
        packAB(c0, c1, ah, al);
#pragma unroll
        for (int nt = 0; nt < 4; ++nt) {
            const uint4* wf = (const uint4*)&fB[((size_t)(ks * 4 + nt) * 64 + l) * 8];
            FragU BH, BL; BH.q = wf[0]; BL.q = wf[1];
            MFMA3(acc[nt], ah, al, BH.v, BL.v);
        }
    }
#pragma unroll
    for (int nt = 0; nt < 4; ++nt)
#pragma unroll
        for (int r = 0; r < 4; ++r)
            bf[(16 * w + 4 * cq + r) * ASTR + nt * 16 + cr] = acc[nt][r];
    __syncthreads();

    // ---- 3-phase scan. slot l = 2p + (re/im); all 8 waves active.
    // phase 1: wave w scans rows [16w, 16w+16) from zero state
    {
        int p = l >> 1;
        float Lr = Lbar[(lay * PD + p) * 2];
        float Lj = Lbar[(lay * PD + p) * 2 + 1];
        float csn = (l & 1) ? Lj : -Lj;
        float xv = 0.0f;
        int t0 = 16 * w;
#pragma unroll
        for (int tl = 0; tl < 16; ++tl) {
            float b = bf[(t0 + tl) * ASTR + l];
            float xo = __shfl_xor(xv, 1, 64);
            xv = Lr * xv + csn * xo + b;
            bf[(t0 + tl) * ASTR + l] = xv;
        }
        agg[w * 64 + l] = xv;
    }
    __syncthreads();
    // phase 2: wave 0 computes exclusive prefixes across the 8 sub-chunks (LC16 = Lbar^16)
    if (w == 0) {
        int p = l >> 1;
        float ldr = lld[2 * p], ldi = lld[2 * p + 1];
        float e16 = __expf(ldr * 16.0f);
        float an = ldi * 16.0f;
        float lcr = e16 * __cosf(an), lci = e16 * __sinf(an);
        float csn16 = (l & 1) ? lci : -lci;
        float pv = 0.0f;
#pragma unroll
        for (int ww = 0; ww < 8; ++ww) {
            pref[ww * 64 + l] = pv;
            float a = agg[ww * 64 + l];
            float po = __shfl_xor(pv, 1, 64);
            pv = lcr * pv + csn16 * po + a;
        }
        carry[(size_t)blockIdx.x * 64 + l] = pv;   // inclusive total = x_127
    }
    __syncthreads();
    // phase 3: wave w (w>0) applies x_t += L^(tl+1) * X_w
    if (w > 0) {
        int p = l >> 1;
        float Lr = Lbar[(lay * PD + p) * 2];
        float Li = Lbar[(lay * PD + p) * 2 + 1];
        float P  = pref[w * 64 + l];
        float Po = __shfl_xor(P, 1, 64);
        float mr = Lr, mi = Li;   // m = L^1
        int t0 = 16 * w;
#pragma unroll
        for (int tl = 0; tl < 16; ++tl) {
            float msn = (l & 1) ? mi : -mi;
            bf[(t0 + tl) * ASTR + l] += mr * P + msn * Po;
            float nmr = mr * Lr - mi * Li;
            float nmi = mr * Li + mi * Lr;
            mr = nmr; mi = nmi;
        }
    }
    __syncthreads();
    // xs store as bf16 (own-wave rows)
#pragma unroll
    for (int j = 0; j < 2; ++j) {
        unsigned uu[4];
#pragma unroll
        for (int q2 = 0; q2 < 4; ++q2) {
            float a = bf[arow * ASTR + cq * 16 + j * 8 + q2 * 2];
            float b = bf[arow * ASTR + cq * 16 + j * 8 + q2 * 2 + 1];
            unsigned ua = (__float_as_uint(a) + 0x8000u) >> 16;
            unsigned ub = (__float_as_uint(b) + 0x8000u) & 0xffff0000u;
            uu[q2] = ua | ub;
        }
        *(uint4*)&xs[(r0 + arow) * HD + cq * 16 + j * 8] =
            make_uint4(uu[0], uu[1], uu[2], uu[3]);
    }
}

// ---------------------------------------------------------------- K3: cross-chunk carry scan
__global__ __launch_bounds__(64) void ssm_k3_carry(
    const float* __restrict__ carry, const float* __restrict__ Ldt,
    float* __restrict__ pc, int lay)
{
    int p = blockIdx.x;
    int lane = threadIdx.x;
    float ldr = Ldt[(lay * PD + p) * 2], ldi = Ldt[(lay * PD + p) * 2 + 1];
    float er = __expf(ldr * (float)CHUNK);
    float an = ldi * (float)CHUNK;
    float lcr = er * __cosf(an), lci = er * __sinf(an);
    float cr[16], ci[16];
#pragma unroll
    for (int j = 0; j < 16; ++j) {
        cr[j] = carry[(size_t)(lane * 16 + j) * 64 + 2 * p];
        ci[j] = carry[(size_t)(lane * 16 + j) * 64 + 2 * p + 1];
    }
    float ur = 0.0f, ui = 0.0f;
#pragma unroll
    for (int j = 0; j < 16; ++j) {
        float nr = lcr * ur - lci * ui + cr[j];
        float ni = lcr * ui + lci * ur + ci[j];
        ur = nr; ui = ni;
    }
    float mr = lcr, mi = lci;
#pragma unroll
    for (int s = 0; s < 4; ++s) { float t = mr * mr - mi * mi; mi = 2.0f * mr * mi; mr = t; }
#pragma unroll
    for (int d = 1; d < 64; d <<= 1) {
        float tr = __shfl_up(ur, d, 64);
        float ti = __shfl_up(ui, d, 64);
        if (lane >= d) { ur = mr * tr - mi * ti + ur; ui = mr * ti + mi * tr + ui; }
        float t = mr * mr - mi * mi; mi = 2.0f * mr * mi; mr = t;
    }
    float pr = __shfl_up(ur, 1, 64), pi = __shfl_up(ui, 1, 64);
    float xr = (lane == 0) ? 0.0f : pr;
    float xi = (lane == 0) ? 0.0f : pi;
#pragma unroll
    for (int j = 0; j < 16; ++j) {
        pc[(size_t)(lane * 16 + j) * 64 + 2 * p]     = xr;
        pc[(size_t)(lane * 16 + j) * 64 + 2 * p + 1] = xi;
        float nr = lcr * xr - lci * xi + cr[j];
        float ni = lcr * xi + lci * xr + ci[j];
        xr = nr; xi = ni;
    }
}

// ---------------------------------------------------------------- K4: fixup + C-proj + gelu + GLU + residual (MFMA); xs read as bf16
template <bool LAST>
__global__ __launch_bounds__(512, 4) void ssm_k4_out(
    const float* __restrict__ h, const unsigned short* __restrict__ xs,
    const float* __restrict__ pc, const float* __restrict__ stats,
    const float* __restrict__ nscale, const float* __restrict__ nbias,
    const float* __restrict__ Ldt, const unsigned* __restrict__ fragL,
    const float* __restrict__ Dv,
    const float* __restrict__ b1, const float* __restrict__ b2,
    float* __restrict__ hout, float* __restrict__ part,
    const float* __restrict__ dec_w, const float* __restrict__ dec_b,
    float* __restrict__ outp, int lay)
{
    __shared__ __attribute__((aligned(16))) unsigned act[128 * ASTR];
    __shared__ float lsa[HD], lsb[HD], lsd[HD], lpc[HD], lld[HD];
    __shared__ float sp1[512], sp2[512];
    int tid = threadIdx.x;
    int l = tid & 63, w = tid >> 6;
    int cq = l >> 4, cr = l & 15;
    size_t r0 = (size_t)blockIdx.x * CHUNK;
    int arow = 16 * w + cr;
    const f32x4 fzero = {0.f, 0.f, 0.f, 0.f};

    if (tid < HD) {
        float s1 = stats[lay * 128 + tid], s2 = stats[lay * 128 + 64 + tid];
        float mu = s1 * (1.0f / T_LEN);
        float var = fmaxf(s2 * (1.0f / T_LEN) - mu * mu, 0.0f);
        float sc = nscale[lay * HD + tid] * rsqrtf(var + 1e-5f);
        lsa[tid] = sc;
        lsb[tid] = nbias[lay * HD + tid] - mu * sc;
        lsd[tid] = Dv[lay * HD + tid];
        lpc[tid] = pc[(size_t)blockIdx.x * 64 + tid];
        lld[tid] = Ldt[lay * 64 + tid];
    }
    __syncthreads();

    // phase 1+2: xs (bf16) direct A-frag load + carry fixup -> C-proj GEMM
    const unsigned* fC = fragL + (size_t)(lay * 4 + 1) * 4096;
    f32x4 yacc[4];
#pragma unroll
    for (int nt = 0; nt < 4; ++nt) yacc[nt] = fzero;
    {
        const unsigned short* xrowp = &xs[(r0 + arow) * HD];
        float tt = (float)(arow + 1);
#pragma unroll
        for (int ks = 0; ks < 2; ++ks) {
            int k0 = ks * 32 + cq * 4;
            uint2 q0 = *(const uint2*)&xrowp[k0];
            uint2 q1 = *(const uint2*)&xrowp[k0 + 16];
            float4 v0 = make_float4(
                __uint_as_float(q0.x << 16), __uint_as_float(q0.x & 0xffff0000u),
                __uint_as_float(q0.y << 16), __uint_as_float(q0.y & 0xffff0000u));
            float4 v1 = make_float4(
                __uint_as_float(q1.x << 16), __uint_as_float(q1.x & 0xffff0000u),
                __uint_as_float(q1.y << 16), __uint_as_float(q1.y & 0xffff0000u));
            {
                float e1 = __expf(lld[k0] * tt), an = lld[k0 + 1] * tt;
                float prr = e1 * __cosf(an), pri = e1 * __sinf(an);
                v0.x += prr * lpc[k0] - pri * lpc[k0 + 1];
                v0.y += prr * lpc[k0 + 1] + pri * lpc[k0];
            }
            {
                float e1 = __expf(lld[k0 + 2] * tt), an = lld[k0 + 3] * tt;
                float prr = e1 * __cosf(an), pri = e1 * __sinf(an);
                v0.z += prr * lpc[k0 + 2] - pri * lpc[k0 + 3];
                v0.w += prr * lpc[k0 + 3] + pri * lpc[k0 + 2];
            }
            {
                float e1 = __expf(lld[k0 + 16] * tt), an = lld[k0 + 17] * tt;
                float prr = e1 * __cosf(an), pri = e1 * __sinf(an);
                v1.x += prr * lpc[k0 + 16] - pri * lpc[k0 + 17];
                v1.y += prr * lpc[k0 + 17] + pri * lpc[k0 + 16];
            }
            {
                float e1 = __expf(lld[k0 + 18] * tt), an = lld[k0 + 19] * tt;
                float prr = e1 * __cosf(an), pri = e1 * __sinf(an);
                v1.z += prr * lpc[k0 + 18] - pri * lpc[k0 + 19];
                v1.w += prr * lpc[k0 + 19] + pri * lpc[k0 + 18];
            }
            bf16x8 ah, al;
            packAB(v0, v1, ah, al);
#pragma unroll
            for (int nt = 0; nt < 4; ++nt) {
                const uint4* wf = (const uint4*)&fC[((size_t)(ks * 4 + nt) * 64 + l) * 8];
                FragU BH, BL; BH.q = wf[0]; BL.q = wf[1];
                MFMA3(yacc[nt], ah, al, BH.v, BL.v);
            }
        }
    }

    // phase 3: h load (C/D positions), gelu(2y + hn*D) -> g split-packed into act
    float hrow[16];
#pragma unroll
    for (int nt = 0; nt < 4; ++nt) {
        int ch = nt * 16 + cr;
        float sav = lsa[ch], sbv = lsb[ch], dvv = lsd[ch];
#pragma unroll
        for (int r = 0; r < 4; ++r) {
            int row = 16 * w + 4 * cq + r;
            float hv = h[(r0 + row) * HD + ch];
            hrow[nt * 4 + r] = hv;
            float t = 2.0f * yacc[nt][r] + (hv * sav + sbv) * dvv;
            float u2 = 1.5957691216057308f * (t + 0.044715f * t * t * t);
            float gv = t / (1.0f + __expf(-u2));
            act[row * ASTR + ch] = splitpack(gv);
        }
    }
    asm volatile("s_waitcnt lgkmcnt(0)" ::: "memory");

    // phase 4: GLU 2 GEMMs (shared A-frags from act)
    const unsigned* f1 = fragL + (size_t)(lay * 4 + 2) * 4096;
    const unsigned* f2 = fragL + (size_t)(lay * 4 + 3) * 4096;
    f32x4 uacc[4], sacc[4];
#pragma unroll
    for (int nt = 0; nt < 4; ++nt) { uacc[nt] = fzero; sacc[nt] = fzero; }
#pragma unroll
    for (int ks = 0; ks < 2; ++ks) {
        int col = ks * 32 + 4 * cq;
        uint4 a0 = *(const uint4*)&act[arow * ASTR + col];
        uint4 a1 = *(const uint4*)&act[arow * ASTR + col + 16];
        union { bf16x8 v; unsigned u[4]; } H, L;
        H.u[0] = (a0.x & 0xffffu) | (a0.y << 16);
        H.u[1] = (a0.z & 0xffffu) | (a0.w << 16);
        H.u[2] = (a1.x & 0xffffu) | (a1.y << 16);
        H.u[3] = (a1.z & 0xffffu) | (a1.w << 16);
        L.u[0] = (a0.x >> 16) | (a0.y & 0xffff0000u);
        L.u[1] = (a0.z >> 16) | (a0.w & 0xffff0000u);
        L.u[2] = (a1.x >> 16) | (a1.y & 0xffff0000u);
        L.u[3] = (a1.z >> 16) | (a1.w & 0xffff0000u);
#pragma unroll
        for (int nt = 0; nt < 4; ++nt) {
            const uint4* w1f = (const uint4*)&f1[((size_t)(ks * 4 + nt) * 64 + l) * 8];
            FragU BH1, BL1; BH1.q = w1f[0]; BL1.q = w1f[1];
            MFMA3(uacc[nt], H.v, L.v, BH1.v, BL1.v);
            const uint4* w2f = (const uint4*)&f2[((size_t)(ks * 4 + nt) * 64 + l) * 8];
            FragU BH2, BL2; BH2.q = w2f[0]; BL2.q = w2f[1];
            MFMA3(sacc[nt], H.v, L.v, BH2.v, BL2.v);
        }
    }

    // phase 5: epilogue
    if (LAST) {
        float o0[4] = {0.f, 0.f, 0.f, 0.f}, o1[4] = {0.f, 0.f, 0.f, 0.f};
#pragma unroll
        for (int nt = 0; nt < 4; ++nt) {
            int ch = nt * 16 + cr;
            float bb1 = b1[lay * HD + ch], bb2 = b2[lay * HD + ch];
            float dw0 = dec_w[ch], dw1 = dec_w[64 + ch];
#pragma unroll
            for (int r = 0; r < 4; ++r) {
                float sv = sacc[nt][r] + bb2;
                float sg = 1.0f / (1.0f + __expf(-sv));
                float ho = hrow[nt * 4 + r] + (uacc[nt][r] + bb1) * sg;
                o0[r] += ho * dw0;
                o1[r] += ho * dw1;
            }
        }
#pragma unroll
        for (int r = 0; r < 4; ++r) {
#pragma unroll
            for (int m = 1; m < 16; m <<= 1) {
                o0[r] += __shfl_xor(o0[r], m, 64);
                o1[r] += __shfl_xor(o1[r], m, 64);
            }
        }
        if (cr == 0) {
            float db0 = dec_b[0], db1 = dec_b[1];
#pragma unroll
            for (int r = 0; r < 4; ++r) {
                int row = 16 * w + 4 * cq + r;
                *(float2*)&outp[(r0 + row) * 2] = make_float2(o0[r] + db0, o1[r] + db1);
            }
        }
    } else {
#pragma unroll
        for (int nt = 0; nt < 4; ++nt) {
            int ch = nt * 16 + cr;
            float bb1 = b1[lay * HD + ch], bb2 = b2[lay * HD + ch];
            float v1 = 0.0f, v2 = 0.0f;
#pragma unroll
            for (int r = 0; r < 4; ++r) {
                int row = 16 * w + 4 * cq + r;
                float sv = sacc[nt][r] + bb2;
                float sg = 1.0f / (1.0f + __expf(-sv));
                float ho = hrow[nt * 4 + r] + (uacc[nt][r] + bb1) * sg;
                hout[(r0 + row) * HD + ch] = ho;
                v1 += ho; v2 += ho * ho;
            }
            v1 += __shfl_xor(v1, 16, 64); v2 += __shfl_xor(v2, 16, 64);
            v1 += __shfl_xor(v1, 32, 64); v2 += __shfl_xor(v2, 32, 64);
            if (l < 16) { sp1[w * 64 + ch] = v1; sp2[w * 64 + ch] = v2; }
        }
        __syncthreads();
        if (tid < 64) {
            float s1 = 0.0f, s2 = 0.0f;
#pragma unroll
            for (int ww = 0; ww < 8; ++ww) { s1 += sp1[ww * 64 + tid]; s2 += sp2[ww * 64 + tid]; }
            part[tid * 1024 + blockIdx.x]        = s1;
            part[(64 + tid) * 1024 + blockIdx.x] = s2;
        }
    }
}

// ---------------------------------------------------------------- launch
extern "C" void kernel_launch(void* const* d_in, const int* in_sizes, int n_in,
                              void* d_out, int out_size, void* d_ws, size_t ws_size,
                              hipStream_t stream)
{
    (void)in_sizes; (void)n_in; (void)out_size; (void)ws_size;
    const float* x     = (const float*)d_in[0];
    const int*   gidx  = (const int*)d_in[1];
    const float* enc_w = (const float*)d_in[2];
    const float* enc_b = (const float*)d_in[3];
    const float* ctx   = (const float*)d_in[4];
    const float* Lre   = (const float*)d_in[5];
    const float* Lim   = (const float*)d_in[6];
    const float* Bre   = (const float*)d_in[7];
    const float* Bim   = (const float*)d_in[8];
    const float* Cre   = (const float*)d_in[9];
    const float* Cim   = (const float*)d_in[10];
    const float* Dv    = (const float*)d_in[11];
    const float* lstep = (const float*)d_in[12];
    const float* nsc   = (const float*)d_in[13];
    const float* nbi   = (const float*)d_in[14];
    const float* w1    = (const float*)d_in[15];
    const float* b1    = (const float*)d_in[16];
    const float* w2    = (const float*)d_in[17];
    const float* b2    = (const float*)d_in[18];
    const float* dw    = (const float*)d_in[19];
    const float* db    = (const float*)d_in[20];
    float* out = (float*)d_out;

    float* ws = (float*)d_ws;
    float* h     = ws;  ws += (size_t)T_LEN * HD;
    unsigned short* xs = (unsigned short*)ws;  ws += (size_t)T_LEN * HD / 2;  // bf16
    float* carry = ws;  ws += (size_t)NBLK * HD;
    float* pc    = ws;  ws += (size_t)NBLK * HD;
    float* stats = ws;  ws += NLAY * 128;
    float* Lbar  = ws;  ws += NLAY * PD * 2;
    float* Ldt   = ws;  ws += NLAY * PD * 2;
    unsigned* fragE = (unsigned*)ws;  ws += 16384;
    unsigned* fragL = (unsigned*)ws;  ws += 65536;
    float* part  = ws;  ws += 128 * 1024;

    ssm_k0a<<<1, 512, 0, stream>>>(Lre, Lim, lstep, Lbar, Ldt, stats);
    ssm_k0b<<<40, 256, 0, stream>>>(Lre, Lim, lstep, Bre, Bim, Cre, Cim, w1, w2,
                                    enc_w, gidx, fragE, fragL);
    ssm_k1_encoder<<<1024, 512, 0, stream>>>(x, gidx, fragE, enc_b, ctx, h, part);
    ssm_k5_reduce<<<128, 64, 0, stream>>>(part, stats);
    for (int lay = 0; lay < NLAY; ++lay) {
        ssm_k2_bu_scan<<<NBLK, 512, 0, stream>>>(h, stats, nsc, nbi, fragL, Lbar, Ldt,
                                                 xs, carry, lay);
        ssm_k3_carry<<<PD, 64, 0, stream>>>(carry, Ldt, pc, lay);
        if (lay < NLAY - 1) {
            ssm_k4_out<false><<<NBLK, 512, 0, stream>>>(
                h, xs, pc, stats, nsc, nbi, Ldt, fragL, Dv, b1, b2,
                h, part, dw, db, out, lay);
            ssm_k5_reduce<<<128, 64, 0, stream>>>(part, stats + (lay + 1) * 128);
        } else {
            ssm_k4_out<true><<<NBLK, 512, 0, stream>>>(
                h, xs, pc, stats, nsc, nbi, Ldt, fragL, Dv, b1, b2,
                h, part, dw, db, out, lay);
        }
    }
}